// Round 1
// baseline (591.946 us; speedup 1.0000x reference)
//
#include <hip/hip_runtime.h>
#include <hip/hip_bf16.h>
#include <cstdint>

// ---------------------------------------------------------------------------
// BasicTransformerBlock: LN -> self-attn -> LN -> cross-attn -> LN -> GEGLU FF
// B=2, N=4096, DIM=512, HEADS=8, D_HEAD=64, CTX: M=256, CD=768, FF_INNER=2048
// Strategy: fp32 residual stream/LN, bf16 MFMA for all GEMMs + flash attention.
// ---------------------------------------------------------------------------

typedef __bf16 bf16_t;
typedef __bf16 bf16x8 __attribute__((ext_vector_type(8)));
typedef float f32x4 __attribute__((ext_vector_type(4)));
typedef unsigned int u32x4 __attribute__((ext_vector_type(4)));

__device__ __forceinline__ bf16_t f2bf(float f) { return (bf16_t)f; }

__device__ __forceinline__ f32x4 mfma16(bf16x8 a, bf16x8 b, f32x4 c) {
  return __builtin_amdgcn_mfma_f32_16x16x32_bf16(a, b, c, 0, 0, 0);
}

__device__ __forceinline__ float gelu_exact(float x) {
  return 0.5f * x * (1.0f + erff(x * 0.70710678118654752f));
}

// ---------------------------------------------------------------------------
// LayerNorm: one wave per row of 512 fp32; writes bf16.
// ---------------------------------------------------------------------------
__global__ __launch_bounds__(256) void ln_kernel(const float* __restrict__ in,
                                                 const float* __restrict__ gw,
                                                 const float* __restrict__ bw,
                                                 bf16_t* __restrict__ out) {
  int w = threadIdx.x >> 6, l = threadIdx.x & 63;
  size_t row = (size_t)blockIdx.x * 4 + w;
  const float* p = in + row * 512 + l * 8;
  f32x4 va = *(const f32x4*)p;
  f32x4 vb = *(const f32x4*)(p + 4);
  float xs[8] = {va[0], va[1], va[2], va[3], vb[0], vb[1], vb[2], vb[3]};
  float s = 0.f;
#pragma unroll
  for (int j = 0; j < 8; j++) s += xs[j];
#pragma unroll
  for (int m = 1; m < 64; m <<= 1) s += __shfl_xor(s, m);
  float mu = s * (1.0f / 512.0f);
  float v = 0.f;
#pragma unroll
  for (int j = 0; j < 8; j++) { float d = xs[j] - mu; v += d * d; }
#pragma unroll
  for (int m = 1; m < 64; m <<= 1) v += __shfl_xor(v, m);
  float rstd = rsqrtf(v * (1.0f / 512.0f) + 1e-5f);
  f32x4 g0 = *(const f32x4*)(gw + l * 8);
  f32x4 g1 = *(const f32x4*)(gw + l * 8 + 4);
  f32x4 b0 = *(const f32x4*)(bw + l * 8);
  f32x4 b1 = *(const f32x4*)(bw + l * 8 + 4);
  bf16x8 o;
#pragma unroll
  for (int j = 0; j < 4; j++) o[j] = f2bf((xs[j] - mu) * rstd * g0[j] + b0[j]);
#pragma unroll
  for (int j = 0; j < 4; j++) o[4 + j] = f2bf((xs[4 + j] - mu) * rstd * g1[j] + b1[j]);
  *(bf16x8*)(out + row * 512 + l * 8) = o;
}

// ---------------------------------------------------------------------------
// Weight transpose+convert: W fp32 [K][N] -> Wt bf16 [N][K]
// ---------------------------------------------------------------------------
__global__ __launch_bounds__(256) void wtrans_kernel(const float* __restrict__ W,
                                                     bf16_t* __restrict__ Wt,
                                                     int K, int N) {
  __shared__ float t[32][33];
  int k0 = blockIdx.x * 32, n0 = blockIdx.y * 32;
#pragma unroll
  for (int i = 0; i < 4; i++) {
    int idx = threadIdx.x + i * 256;
    int kk = idx >> 5, nn = idx & 31;
    t[kk][nn] = W[(size_t)(k0 + kk) * N + n0 + nn];
  }
  __syncthreads();
#pragma unroll
  for (int i = 0; i < 4; i++) {
    int idx = threadIdx.x + i * 256;
    int nn = idx >> 5, kk = idx & 31;
    Wt[(size_t)(n0 + nn) * K + k0 + kk] = f2bf(t[kk][nn]);
  }
}

// fp32 -> bf16 elementwise (n multiple of 1024)
__global__ __launch_bounds__(256) void cvt_kernel(const float* __restrict__ in,
                                                  bf16_t* __restrict__ out) {
  int i = (blockIdx.x * 256 + threadIdx.x) * 4;
  f32x4 v = *(const f32x4*)(in + i);
  out[i + 0] = f2bf(v[0]);
  out[i + 1] = f2bf(v[1]);
  out[i + 2] = f2bf(v[2]);
  out[i + 3] = f2bf(v[3]);
}

// ---------------------------------------------------------------------------
// GEMM: C[M][N] = A[M][K](bf16) @ B (given as Bt bf16 [N][K]).
// BM=128, BK=32, 256 threads, 2x2 wave grid.
// EPI 0: write bf16 out.
// EPI 1: write fp32 out = acc + bias[col] + res[row*ldo+col].
// EPI 2 (BN=64): GEGLU: val=acc+bias[col], gate=acc2+bias[col+gateOff],
//                out bf16 = val * gelu(gate). Gate cols from Bt rows n0+gateOff.
// ---------------------------------------------------------------------------
template <int BN, int EPI>
__global__ __launch_bounds__(256) void gemm_kernel(
    const bf16_t* __restrict__ A, const bf16_t* __restrict__ Bt,
    const float* __restrict__ bias, const float* __restrict__ res,
    void* __restrict__ outp, int M, int N, int K, int gateOff, int ldo) {
  constexpr int WN = BN / 2;
  constexpr int NF = WN / 16;
  constexpr int LDT = 48;  // 32 + 16 pad: 96B rows, 16B-aligned, low conflict
  __shared__ bf16_t Al[128][LDT];
  __shared__ bf16_t Bl[(EPI == 2 ? 2 * BN : BN)][LDT];

  int tid = threadIdx.x;
  int w = tid >> 6, l = tid & 63;
  int wr = w >> 1, wc = w & 1;
  int lg = l >> 4, lc = l & 15;
  int m0 = blockIdx.x * 128, n0 = blockIdx.y * BN;

  f32x4 acc[4][NF] = {};
  f32x4 acc2[4][NF] = {};

  int arow = tid >> 1, akc = (tid & 1) * 16;

  for (int k0 = 0; k0 < K; k0 += 32) {
    const bf16_t* asrc = A + (size_t)(m0 + arow) * K + k0 + akc;
    u32x4 a0 = *(const u32x4*)asrc;
    u32x4 a1 = *(const u32x4*)(asrc + 8);
    if (BN == 128) {
      const bf16_t* bsrc = Bt + (size_t)(n0 + arow) * K + k0 + akc;
      u32x4 bb0 = *(const u32x4*)bsrc;
      u32x4 bb1 = *(const u32x4*)(bsrc + 8);
      __syncthreads();
      *(u32x4*)&Al[arow][akc] = a0;
      *(u32x4*)&Al[arow][akc + 8] = a1;
      *(u32x4*)&Bl[arow][akc] = bb0;
      *(u32x4*)&Bl[arow][akc + 8] = bb1;
    } else {
      int brow = tid >> 2, bkc = (tid & 3) * 8;
      u32x4 bb0 = *(const u32x4*)(Bt + (size_t)(n0 + brow) * K + k0 + bkc);
      u32x4 bb1 = {};
      if (EPI == 2)
        bb1 = *(const u32x4*)(Bt + (size_t)(n0 + gateOff + brow) * K + k0 + bkc);
      __syncthreads();
      *(u32x4*)&Al[arow][akc] = a0;
      *(u32x4*)&Al[arow][akc + 8] = a1;
      *(u32x4*)&Bl[brow][bkc] = bb0;
      if (EPI == 2) *(u32x4*)&Bl[BN + brow][bkc] = bb1;
    }
    __syncthreads();

    bf16x8 af[4];
#pragma unroll
    for (int mi = 0; mi < 4; mi++)
      af[mi] = *(const bf16x8*)&Al[wr * 64 + mi * 16 + lc][lg * 8];
    bf16x8 bfr[NF];
#pragma unroll
    for (int ni = 0; ni < NF; ni++)
      bfr[ni] = *(const bf16x8*)&Bl[wc * WN + ni * 16 + lc][lg * 8];
#pragma unroll
    for (int mi = 0; mi < 4; mi++)
#pragma unroll
      for (int ni = 0; ni < NF; ni++)
        acc[mi][ni] = mfma16(af[mi], bfr[ni], acc[mi][ni]);
    if (EPI == 2) {
      bf16x8 bg[NF];
#pragma unroll
      for (int ni = 0; ni < NF; ni++)
        bg[ni] = *(const bf16x8*)&Bl[BN + wc * WN + ni * 16 + lc][lg * 8];
#pragma unroll
      for (int mi = 0; mi < 4; mi++)
#pragma unroll
        for (int ni = 0; ni < NF; ni++)
          acc2[mi][ni] = mfma16(af[mi], bg[ni], acc2[mi][ni]);
    }
    __syncthreads();
  }

#pragma unroll
  for (int mi = 0; mi < 4; mi++) {
#pragma unroll
    for (int ni = 0; ni < NF; ni++) {
#pragma unroll
      for (int r = 0; r < 4; r++) {
        int row = m0 + wr * 64 + mi * 16 + lg * 4 + r;
        int col = n0 + wc * WN + ni * 16 + lc;
        float v = acc[mi][ni][r];
        if (EPI == 0) {
          ((bf16_t*)outp)[(size_t)row * ldo + col] = f2bf(v);
        } else if (EPI == 1) {
          ((float*)outp)[(size_t)row * ldo + col] =
              v + bias[col] + res[(size_t)row * ldo + col];
        } else {
          float g = acc2[mi][ni][r] + bias[col + gateOff];
          float val = v + bias[col];
          ((bf16_t*)outp)[(size_t)row * ldo + col] = f2bf(val * gelu_exact(g));
        }
      }
    }
  }
}

// ---------------------------------------------------------------------------
// Flash attention. Block = 256 threads (4 waves); each block: one (b, head,
// 64 q-rows); each wave owns 16 q-rows. KV iterated in tiles of 64.
// Q,K,V,O layout: [B*tokens][512] bf16, head h at cols h*64..h*64+63.
// ---------------------------------------------------------------------------
__global__ __launch_bounds__(256) void attn_kernel(
    const bf16_t* __restrict__ Q, const bf16_t* __restrict__ Kb,
    const bf16_t* __restrict__ Vb, bf16_t* __restrict__ O, int Mkv) {
  __shared__ bf16_t Klds[64][72];
  __shared__ bf16_t Vt[64][72];
  __shared__ bf16_t Plds[4][16][72];

  int qt = blockIdx.x, head = blockIdx.y, b = blockIdx.z;
  int tid = threadIdx.x;
  int w = tid >> 6, l = tid & 63;
  int lg = l >> 4, lc = l & 15;

  // Q fragments (A-operand): row = lc, k = lg*8+j within each 32-wide half
  size_t qtok = (size_t)b * 4096 + qt * 64 + w * 16 + lc;
  const bf16_t* qp = Q + qtok * 512 + head * 64;
  bf16x8 aq0 = *(const bf16x8*)(qp + lg * 8);
  bf16x8 aq1 = *(const bf16x8*)(qp + 32 + lg * 8);

  f32x4 o[4] = {};
  float mrun[4] = {-INFINITY, -INFINITY, -INFINITY, -INFINITY};
  float lrun[4] = {};

  int key0 = tid >> 2, dc0 = (tid & 3) * 16;

  for (int t0 = 0; t0 < Mkv; t0 += 64) {
    size_t ktok = (size_t)b * Mkv + t0 + key0;
    const bf16_t* kp = Kb + ktok * 512 + head * 64 + dc0;
    bf16x8 kv0 = *(const bf16x8*)kp;
    bf16x8 kv1 = *(const bf16x8*)(kp + 8);
    const bf16_t* vp = Vb + ktok * 512 + head * 64 + dc0;
    bf16x8 vv0 = *(const bf16x8*)vp;
    bf16x8 vv1 = *(const bf16x8*)(vp + 8);
    __syncthreads();  // previous tile's LDS reads complete
    *(bf16x8*)&Klds[key0][dc0] = kv0;
    *(bf16x8*)&Klds[key0][dc0 + 8] = kv1;
#pragma unroll
    for (int j = 0; j < 8; j++) Vt[dc0 + j][key0] = vv0[j];
#pragma unroll
    for (int j = 0; j < 8; j++) Vt[dc0 + 8 + j][key0] = vv1[j];
    __syncthreads();

    // S = Q K^T * scale   (4 key-group fragments of 16)
    f32x4 s[4];
#pragma unroll
    for (int kg = 0; kg < 4; kg++) {
      bf16x8 bk0 = *(const bf16x8*)&Klds[kg * 16 + lc][lg * 8];
      bf16x8 bk1 = *(const bf16x8*)&Klds[kg * 16 + lc][32 + lg * 8];
      f32x4 z = {};
      z = mfma16(aq0, bk0, z);
      z = mfma16(aq1, bk1, z);
      s[kg] = z * 0.125f;
    }

    // online softmax (row r lives at (lane>>4)*4+r across 16-lane groups)
    float tmax[4];
#pragma unroll
    for (int r = 0; r < 4; r++)
      tmax[r] = fmaxf(fmaxf(s[0][r], s[1][r]), fmaxf(s[2][r], s[3][r]));
#pragma unroll
    for (int m = 1; m < 16; m <<= 1)
#pragma unroll
      for (int r = 0; r < 4; r++) tmax[r] = fmaxf(tmax[r], __shfl_xor(tmax[r], m));
    float mnew[4], resc[4], tsum[4] = {};
#pragma unroll
    for (int r = 0; r < 4; r++) {
      mnew[r] = fmaxf(mrun[r], tmax[r]);
      resc[r] = __expf(mrun[r] - mnew[r]);
      mrun[r] = mnew[r];
    }
#pragma unroll
    for (int kg = 0; kg < 4; kg++)
#pragma unroll
      for (int r = 0; r < 4; r++) {
        float p = __expf(s[kg][r] - mnew[r]);
        s[kg][r] = p;
        tsum[r] += p;
      }
#pragma unroll
    for (int m = 1; m < 16; m <<= 1)
#pragma unroll
      for (int r = 0; r < 4; r++) tsum[r] += __shfl_xor(tsum[r], m);
#pragma unroll
    for (int r = 0; r < 4; r++) lrun[r] = lrun[r] * resc[r] + tsum[r];
#pragma unroll
    for (int df = 0; df < 4; df++)
#pragma unroll
      for (int r = 0; r < 4; r++) o[df][r] *= resc[r];

    // repack P (C-layout) -> A-layout via wave-private LDS
#pragma unroll
    for (int kg = 0; kg < 4; kg++)
#pragma unroll
      for (int r = 0; r < 4; r++)
        Plds[w][lg * 4 + r][kg * 16 + lc] = f2bf(s[kg][r]);
    bf16x8 pa0 = *(const bf16x8*)&Plds[w][lc][lg * 8];
    bf16x8 pa1 = *(const bf16x8*)&Plds[w][lc][32 + lg * 8];
#pragma unroll
    for (int df = 0; df < 4; df++) {
      bf16x8 vb0 = *(const bf16x8*)&Vt[df * 16 + lc][lg * 8];
      bf16x8 vb1 = *(const bf16x8*)&Vt[df * 16 + lc][32 + lg * 8];
      o[df] = mfma16(pa0, vb0, o[df]);
      o[df] = mfma16(pa1, vb1, o[df]);
    }
  }

  float inv[4];
#pragma unroll
  for (int r = 0; r < 4; r++) inv[r] = 1.0f / lrun[r];
  size_t obase = ((size_t)b * 4096 + qt * 64 + w * 16) * 512 + head * 64;
#pragma unroll
  for (int df = 0; df < 4; df++)
#pragma unroll
    for (int r = 0; r < 4; r++)
      O[obase + (size_t)(lg * 4 + r) * 512 + df * 16 + lc] =
          f2bf(o[df][r] * inv[r]);
}

// ---------------------------------------------------------------------------
extern "C" void kernel_launch(void* const* d_in, const int* in_sizes, int n_in,
                              void* d_out, int out_size, void* d_ws,
                              size_t ws_size, hipStream_t stream) {
  const float* x = (const float*)d_in[0];
  const float* ctx = (const float*)d_in[1];
  const float* q1_w = (const float*)d_in[2];
  const float* k1_w = (const float*)d_in[3];
  const float* v1_w = (const float*)d_in[4];
  const float* o1_w = (const float*)d_in[5];
  const float* o1_b = (const float*)d_in[6];
  const float* q2_w = (const float*)d_in[7];
  const float* k2_w = (const float*)d_in[8];
  const float* v2_w = (const float*)d_in[9];
  const float* o2_w = (const float*)d_in[10];
  const float* o2_b = (const float*)d_in[11];
  const float* ff_in_w = (const float*)d_in[12];
  const float* ff_in_b = (const float*)d_in[13];
  const float* ff_out_w = (const float*)d_in[14];
  const float* ff_out_b = (const float*)d_in[15];
  const float* ln1_g = (const float*)d_in[16];
  const float* ln1_b = (const float*)d_in[17];
  const float* ln2_g = (const float*)d_in[18];
  const float* ln2_b = (const float*)d_in[19];
  const float* ln3_g = (const float*)d_in[20];
  const float* ln3_b = (const float*)d_in[21];

  char* ws = (char*)d_ws;
  float* xr = (float*)(ws + 0);                    // 16.78 MB fp32 residual
  bf16_t* hb = (bf16_t*)(ws + 16777216);           // 8.39 MB LN output
  bf16_t* qb = (bf16_t*)(ws + 25165824);           // 8.39 MB
  bf16_t* kb = (bf16_t*)(ws + 33554432);           // 8.39 MB
  bf16_t* vb = (bf16_t*)(ws + 41943040);           // 8.39 MB
  bf16_t* ao = (bf16_t*)(ws + 50331648);           // 8.39 MB
  bf16_t* ffmid = qb;                              // aliases qb..ao (33.55 MB)
  bf16_t* ctxb = (bf16_t*)(ws + 58720256);         // 0.79 MB
  bf16_t* wts = (bf16_t*)(ws + 59506688);          // 11.01 MB bf16 weights^T

  bf16_t* q1t = wts + 0;
  bf16_t* k1t = wts + 262144;
  bf16_t* v1t = wts + 524288;
  bf16_t* o1t = wts + 786432;
  bf16_t* q2t = wts + 1048576;
  bf16_t* k2t = wts + 1310720;
  bf16_t* v2t = wts + 1703936;
  bf16_t* o2t = wts + 2097152;
  bf16_t* ffint = wts + 2359296;
  bf16_t* ffoutt = wts + 4456448;

  // weight transposes fp32[K][N] -> bf16[N][K]
  wtrans_kernel<<<dim3(16, 16), 256, 0, stream>>>(q1_w, q1t, 512, 512);
  wtrans_kernel<<<dim3(16, 16), 256, 0, stream>>>(k1_w, k1t, 512, 512);
  wtrans_kernel<<<dim3(16, 16), 256, 0, stream>>>(v1_w, v1t, 512, 512);
  wtrans_kernel<<<dim3(16, 16), 256, 0, stream>>>(o1_w, o1t, 512, 512);
  wtrans_kernel<<<dim3(16, 16), 256, 0, stream>>>(q2_w, q2t, 512, 512);
  wtrans_kernel<<<dim3(24, 16), 256, 0, stream>>>(k2_w, k2t, 768, 512);
  wtrans_kernel<<<dim3(24, 16), 256, 0, stream>>>(v2_w, v2t, 768, 512);
  wtrans_kernel<<<dim3(16, 16), 256, 0, stream>>>(o2_w, o2t, 512, 512);
  wtrans_kernel<<<dim3(16, 128), 256, 0, stream>>>(ff_in_w, ffint, 512, 4096);
  wtrans_kernel<<<dim3(64, 16), 256, 0, stream>>>(ff_out_w, ffoutt, 2048, 512);
  cvt_kernel<<<384, 256, 0, stream>>>(ctx, ctxb);  // 2*256*768

  // ---- self-attention ----
  ln_kernel<<<2048, 256, 0, stream>>>(x, ln1_g, ln1_b, hb);
  gemm_kernel<128, 0><<<dim3(64, 4), 256, 0, stream>>>(
      hb, q1t, nullptr, nullptr, qb, 8192, 512, 512, 0, 512);
  gemm_kernel<128, 0><<<dim3(64, 4), 256, 0, stream>>>(
      hb, k1t, nullptr, nullptr, kb, 8192, 512, 512, 0, 512);
  gemm_kernel<128, 0><<<dim3(64, 4), 256, 0, stream>>>(
      hb, v1t, nullptr, nullptr, vb, 8192, 512, 512, 0, 512);
  attn_kernel<<<dim3(64, 8, 2), 256, 0, stream>>>(qb, kb, vb, ao, 4096);
  gemm_kernel<128, 1><<<dim3(64, 4), 256, 0, stream>>>(
      ao, o1t, o1_b, x, xr, 8192, 512, 512, 0, 512);

  // ---- cross-attention ----
  ln_kernel<<<2048, 256, 0, stream>>>(xr, ln2_g, ln2_b, hb);
  gemm_kernel<128, 0><<<dim3(64, 4), 256, 0, stream>>>(
      hb, q2t, nullptr, nullptr, qb, 8192, 512, 512, 0, 512);
  gemm_kernel<128, 0><<<dim3(4, 4), 256, 0, stream>>>(
      ctxb, k2t, nullptr, nullptr, kb, 512, 512, 768, 0, 512);
  gemm_kernel<128, 0><<<dim3(4, 4), 256, 0, stream>>>(
      ctxb, v2t, nullptr, nullptr, vb, 512, 512, 768, 0, 512);
  attn_kernel<<<dim3(64, 8, 2), 256, 0, stream>>>(qb, kb, vb, ao, 256);
  gemm_kernel<128, 1><<<dim3(64, 4), 256, 0, stream>>>(
      ao, o2t, o2_b, xr, xr, 8192, 512, 512, 0, 512);

  // ---- GEGLU FF ----
  ln_kernel<<<2048, 256, 0, stream>>>(xr, ln3_g, ln3_b, hb);
  gemm_kernel<64, 2><<<dim3(64, 32), 256, 0, stream>>>(
      hb, ffint, ff_in_b, nullptr, ffmid, 8192, 2048, 512, 2048, 2048);
  gemm_kernel<128, 1><<<dim3(64, 4), 256, 0, stream>>>(
      ffmid, ffoutt, ff_out_b, xr, (float*)d_out, 8192, 512, 2048, 0, 512);
}

// Round 2
// 498.257 us; speedup vs baseline: 1.1880x; 1.1880x over previous
//
#include <hip/hip_runtime.h>
#include <hip/hip_bf16.h>
#include <cstdint>

// ---------------------------------------------------------------------------
// BasicTransformerBlock: LN -> self-attn -> LN -> cross-attn -> LN -> GEGLU FF
// B=2, N=4096, DIM=512, HEADS=8, D_HEAD=64, CTX: M=256, CD=768, FF_INNER=2048
// fp32 residual/LN, bf16 MFMA GEMMs + flash attention.
// R2: V produced transposed in global (V^T GEMM), row-sum via ones-MFMA,
//     exp2-domain softmax, setprio around MFMA clusters.
// ---------------------------------------------------------------------------

typedef __bf16 bf16_t;
typedef __bf16 bf16x8 __attribute__((ext_vector_type(8)));
typedef float f32x4 __attribute__((ext_vector_type(4)));
typedef unsigned int u32x4 __attribute__((ext_vector_type(4)));

__device__ __forceinline__ bf16_t f2bf(float f) { return (bf16_t)f; }

__device__ __forceinline__ f32x4 mfma16(bf16x8 a, bf16x8 b, f32x4 c) {
  return __builtin_amdgcn_mfma_f32_16x16x32_bf16(a, b, c, 0, 0, 0);
}

__device__ __forceinline__ float gelu_exact(float x) {
  return 0.5f * x * (1.0f + erff(x * 0.70710678118654752f));
}

// ---------------------------------------------------------------------------
// LayerNorm: one wave per row of 512 fp32; writes bf16.
// ---------------------------------------------------------------------------
__global__ __launch_bounds__(256) void ln_kernel(const float* __restrict__ in,
                                                 const float* __restrict__ gw,
                                                 const float* __restrict__ bw,
                                                 bf16_t* __restrict__ out) {
  int w = threadIdx.x >> 6, l = threadIdx.x & 63;
  size_t row = (size_t)blockIdx.x * 4 + w;
  const float* p = in + row * 512 + l * 8;
  f32x4 va = *(const f32x4*)p;
  f32x4 vb = *(const f32x4*)(p + 4);
  float xs[8] = {va[0], va[1], va[2], va[3], vb[0], vb[1], vb[2], vb[3]};
  float s = 0.f;
#pragma unroll
  for (int j = 0; j < 8; j++) s += xs[j];
#pragma unroll
  for (int m = 1; m < 64; m <<= 1) s += __shfl_xor(s, m);
  float mu = s * (1.0f / 512.0f);
  float v = 0.f;
#pragma unroll
  for (int j = 0; j < 8; j++) { float d = xs[j] - mu; v += d * d; }
#pragma unroll
  for (int m = 1; m < 64; m <<= 1) v += __shfl_xor(v, m);
  float rstd = rsqrtf(v * (1.0f / 512.0f) + 1e-5f);
  f32x4 g0 = *(const f32x4*)(gw + l * 8);
  f32x4 g1 = *(const f32x4*)(gw + l * 8 + 4);
  f32x4 b0 = *(const f32x4*)(bw + l * 8);
  f32x4 b1 = *(const f32x4*)(bw + l * 8 + 4);
  bf16x8 o;
#pragma unroll
  for (int j = 0; j < 4; j++) o[j] = f2bf((xs[j] - mu) * rstd * g0[j] + b0[j]);
#pragma unroll
  for (int j = 0; j < 4; j++) o[4 + j] = f2bf((xs[4 + j] - mu) * rstd * g1[j] + b1[j]);
  *(bf16x8*)(out + row * 512 + l * 8) = o;
}

// ---------------------------------------------------------------------------
// Weight transpose+convert: W fp32 [K][N] -> Wt bf16 [N][K]
// ---------------------------------------------------------------------------
__global__ __launch_bounds__(256) void wtrans_kernel(const float* __restrict__ W,
                                                     bf16_t* __restrict__ Wt,
                                                     int K, int N) {
  __shared__ float t[32][33];
  int k0 = blockIdx.x * 32, n0 = blockIdx.y * 32;
#pragma unroll
  for (int i = 0; i < 4; i++) {
    int idx = threadIdx.x + i * 256;
    int kk = idx >> 5, nn = idx & 31;
    t[kk][nn] = W[(size_t)(k0 + kk) * N + n0 + nn];
  }
  __syncthreads();
#pragma unroll
  for (int i = 0; i < 4; i++) {
    int idx = threadIdx.x + i * 256;
    int nn = idx >> 5, kk = idx & 31;
    Wt[(size_t)(n0 + nn) * K + k0 + kk] = f2bf(t[kk][nn]);
  }
}

// fp32 -> bf16 elementwise (n multiple of 1024)
__global__ __launch_bounds__(256) void cvt_kernel(const float* __restrict__ in,
                                                  bf16_t* __restrict__ out) {
  int i = (blockIdx.x * 256 + threadIdx.x) * 4;
  f32x4 v = *(const f32x4*)(in + i);
  out[i + 0] = f2bf(v[0]);
  out[i + 1] = f2bf(v[1]);
  out[i + 2] = f2bf(v[2]);
  out[i + 3] = f2bf(v[3]);
}

// ---------------------------------------------------------------------------
// GEMM: C[M][N] = A[M][K](bf16) @ B (given as Bt bf16 [N][K]).
// BM=128, BK=32, 256 threads, 2x2 wave grid.
// EPI 0: write bf16 out.
// EPI 1: write fp32 out = acc + bias[col] + res[row*ldo+col].
// EPI 2 (BN=64): GEGLU: val=acc+bias[col], gate=acc2+bias[col+gateOff],
//                out bf16 = val * gelu(gate).
// ---------------------------------------------------------------------------
template <int BN, int EPI>
__global__ __launch_bounds__(256) void gemm_kernel(
    const bf16_t* __restrict__ A, const bf16_t* __restrict__ Bt,
    const float* __restrict__ bias, const float* __restrict__ res,
    void* __restrict__ outp, int M, int N, int K, int gateOff, int ldo) {
  constexpr int WN = BN / 2;
  constexpr int NF = WN / 16;
  constexpr int LDT = 48;
  __shared__ bf16_t Al[128][LDT];
  __shared__ bf16_t Bl[(EPI == 2 ? 2 * BN : BN)][LDT];

  int tid = threadIdx.x;
  int w = tid >> 6, l = tid & 63;
  int wr = w >> 1, wc = w & 1;
  int lg = l >> 4, lc = l & 15;
  int m0 = blockIdx.x * 128, n0 = blockIdx.y * BN;

  f32x4 acc[4][NF] = {};
  f32x4 acc2[4][NF] = {};

  int arow = tid >> 1, akc = (tid & 1) * 16;

  for (int k0 = 0; k0 < K; k0 += 32) {
    const bf16_t* asrc = A + (size_t)(m0 + arow) * K + k0 + akc;
    u32x4 a0 = *(const u32x4*)asrc;
    u32x4 a1 = *(const u32x4*)(asrc + 8);
    if (BN == 128) {
      const bf16_t* bsrc = Bt + (size_t)(n0 + arow) * K + k0 + akc;
      u32x4 bb0 = *(const u32x4*)bsrc;
      u32x4 bb1 = *(const u32x4*)(bsrc + 8);
      __syncthreads();
      *(u32x4*)&Al[arow][akc] = a0;
      *(u32x4*)&Al[arow][akc + 8] = a1;
      *(u32x4*)&Bl[arow][akc] = bb0;
      *(u32x4*)&Bl[arow][akc + 8] = bb1;
    } else {
      int brow = tid >> 2, bkc = (tid & 3) * 8;
      u32x4 bb0 = *(const u32x4*)(Bt + (size_t)(n0 + brow) * K + k0 + bkc);
      u32x4 bb1 = {};
      if (EPI == 2)
        bb1 = *(const u32x4*)(Bt + (size_t)(n0 + gateOff + brow) * K + k0 + bkc);
      __syncthreads();
      *(u32x4*)&Al[arow][akc] = a0;
      *(u32x4*)&Al[arow][akc + 8] = a1;
      *(u32x4*)&Bl[brow][bkc] = bb0;
      if (EPI == 2) *(u32x4*)&Bl[BN + brow][bkc] = bb1;
    }
    __syncthreads();

    bf16x8 af[4];
#pragma unroll
    for (int mi = 0; mi < 4; mi++)
      af[mi] = *(const bf16x8*)&Al[wr * 64 + mi * 16 + lc][lg * 8];
    bf16x8 bfr[NF];
#pragma unroll
    for (int ni = 0; ni < NF; ni++)
      bfr[ni] = *(const bf16x8*)&Bl[wc * WN + ni * 16 + lc][lg * 8];
#pragma unroll
    for (int mi = 0; mi < 4; mi++)
#pragma unroll
      for (int ni = 0; ni < NF; ni++)
        acc[mi][ni] = mfma16(af[mi], bfr[ni], acc[mi][ni]);
    if (EPI == 2) {
      bf16x8 bg[NF];
#pragma unroll
      for (int ni = 0; ni < NF; ni++)
        bg[ni] = *(const bf16x8*)&Bl[BN + wc * WN + ni * 16 + lc][lg * 8];
#pragma unroll
      for (int mi = 0; mi < 4; mi++)
#pragma unroll
        for (int ni = 0; ni < NF; ni++)
          acc2[mi][ni] = mfma16(af[mi], bg[ni], acc2[mi][ni]);
    }
    __syncthreads();
  }

#pragma unroll
  for (int mi = 0; mi < 4; mi++) {
#pragma unroll
    for (int ni = 0; ni < NF; ni++) {
#pragma unroll
      for (int r = 0; r < 4; r++) {
        int row = m0 + wr * 64 + mi * 16 + lg * 4 + r;
        int col = n0 + wc * WN + ni * 16 + lc;
        float v = acc[mi][ni][r];
        if (EPI == 0) {
          ((bf16_t*)outp)[(size_t)row * ldo + col] = f2bf(v);
        } else if (EPI == 1) {
          ((float*)outp)[(size_t)row * ldo + col] =
              v + bias[col] + res[(size_t)row * ldo + col];
        } else {
          float g = acc2[mi][ni][r] + bias[col + gateOff];
          float val = v + bias[col];
          ((bf16_t*)outp)[(size_t)row * ldo + col] = f2bf(val * gelu_exact(g));
        }
      }
    }
  }
}

// ---------------------------------------------------------------------------
// Flash attention v2. Block = 256 threads (4 waves); one (b, head, 64 q-rows)
// per block; each wave owns 16 q-rows. KV tiles of 64.
// Q,K layout: [B*tokens][512] bf16 (head h at cols h*64..). V is pre-
// transposed in GLOBAL memory: Vt[vdim=h*64+d][B*Mkv tokens] (ldv = 2*Mkv).
// Softmax in exp2 domain; row-sums via ones-MFMA on repacked P.
// ---------------------------------------------------------------------------
__global__ __launch_bounds__(256) void attn_kernel(
    const bf16_t* __restrict__ Q, const bf16_t* __restrict__ Kb,
    const bf16_t* __restrict__ Vt, bf16_t* __restrict__ O, int Mkv) {
  __shared__ bf16_t Klds[64][72];
  __shared__ bf16_t Vlds[64][72];  // rows = d, cols = key
  __shared__ bf16_t Plds[4][16][72];

  int qt = blockIdx.x, head = blockIdx.y, b = blockIdx.z;
  int tid = threadIdx.x;
  int w = tid >> 6, l = tid & 63;
  int lg = l >> 4, lc = l & 15;
  int ldv = 2 * Mkv;

  size_t qtok = (size_t)b * 4096 + qt * 64 + w * 16 + lc;
  const bf16_t* qp = Q + qtok * 512 + head * 64;
  bf16x8 aq0 = *(const bf16x8*)(qp + lg * 8);
  bf16x8 aq1 = *(const bf16x8*)(qp + 32 + lg * 8);

  f32x4 o[4] = {};
  f32x4 zacc = {};  // running row-sum (every col equal)
  float mrun[4] = {-INFINITY, -INFINITY, -INFINITY, -INFINITY};

  bf16x8 vones;
#pragma unroll
  for (int j = 0; j < 8; j++) vones[j] = f2bf(1.0f);

  int key0 = tid >> 2, dc0 = (tid & 3) * 16;  // K staging: row=key
  const float SC = 0.125f * 1.44269504f;      // scale * log2(e)

  for (int t0 = 0; t0 < Mkv; t0 += 64) {
    const bf16_t* kp = Kb + ((size_t)b * Mkv + t0 + key0) * 512 + head * 64 + dc0;
    bf16x8 kv0 = *(const bf16x8*)kp;
    bf16x8 kv1 = *(const bf16x8*)(kp + 8);
    const bf16_t* vp = Vt + (size_t)(head * 64 + key0) * ldv + b * Mkv + t0 + dc0;
    bf16x8 vv0 = *(const bf16x8*)vp;
    bf16x8 vv1 = *(const bf16x8*)(vp + 8);
    __syncthreads();  // previous tile's LDS reads complete
    *(bf16x8*)&Klds[key0][dc0] = kv0;
    *(bf16x8*)&Klds[key0][dc0 + 8] = kv1;
    *(bf16x8*)&Vlds[key0][dc0] = vv0;  // row = d (key0 reused as d index)
    *(bf16x8*)&Vlds[key0][dc0 + 8] = vv1;
    __syncthreads();

    // S = Q K^T * scale (log2 domain)
    f32x4 s[4];
    __builtin_amdgcn_s_setprio(1);
#pragma unroll
    for (int kg = 0; kg < 4; kg++) {
      bf16x8 bk0 = *(const bf16x8*)&Klds[kg * 16 + lc][lg * 8];
      bf16x8 bk1 = *(const bf16x8*)&Klds[kg * 16 + lc][32 + lg * 8];
      f32x4 z = {};
      z = mfma16(aq0, bk0, z);
      z = mfma16(aq1, bk1, z);
      s[kg] = z * SC;
    }
    __builtin_amdgcn_s_setprio(0);

    // online softmax: row r lives at q-row (lg*4+r) across 16-lane groups
    float tmax[4];
#pragma unroll
    for (int r = 0; r < 4; r++)
      tmax[r] = fmaxf(fmaxf(s[0][r], s[1][r]), fmaxf(s[2][r], s[3][r]));
#pragma unroll
    for (int m = 1; m < 16; m <<= 1)
#pragma unroll
      for (int r = 0; r < 4; r++) tmax[r] = fmaxf(tmax[r], __shfl_xor(tmax[r], m));
    float mnew[4], resc[4];
#pragma unroll
    for (int r = 0; r < 4; r++) {
      mnew[r] = fmaxf(mrun[r], tmax[r]);
      resc[r] = exp2f(mrun[r] - mnew[r]);
      mrun[r] = mnew[r];
    }
    // P = exp2(s - mnew), repack C-layout -> A-layout via wave-private LDS
#pragma unroll
    for (int kg = 0; kg < 4; kg++)
#pragma unroll
      for (int r = 0; r < 4; r++)
        Plds[w][lg * 4 + r][kg * 16 + lc] = f2bf(exp2f(s[kg][r] - mnew[r]));
#pragma unroll
    for (int df = 0; df < 4; df++)
#pragma unroll
      for (int r = 0; r < 4; r++) o[df][r] *= resc[r];
#pragma unroll
    for (int r = 0; r < 4; r++) zacc[r] *= resc[r];

    bf16x8 pa0 = *(const bf16x8*)&Plds[w][lc][lg * 8];
    bf16x8 pa1 = *(const bf16x8*)&Plds[w][lc][32 + lg * 8];
    __builtin_amdgcn_s_setprio(1);
    zacc = mfma16(pa0, vones, zacc);  // row-sums (replaces shfl reduction)
    zacc = mfma16(pa1, vones, zacc);
#pragma unroll
    for (int df = 0; df < 4; df++) {
      bf16x8 vb0 = *(const bf16x8*)&Vlds[df * 16 + lc][lg * 8];
      bf16x8 vb1 = *(const bf16x8*)&Vlds[df * 16 + lc][32 + lg * 8];
      o[df] = mfma16(pa0, vb0, o[df]);
      o[df] = mfma16(pa1, vb1, o[df]);
    }
    __builtin_amdgcn_s_setprio(0);
  }

  float inv[4];
#pragma unroll
  for (int r = 0; r < 4; r++) inv[r] = 1.0f / zacc[r];
  size_t obase = ((size_t)b * 4096 + qt * 64 + w * 16) * 512 + head * 64;
#pragma unroll
  for (int df = 0; df < 4; df++)
#pragma unroll
    for (int r = 0; r < 4; r++)
      O[obase + (size_t)(lg * 4 + r) * 512 + df * 16 + lc] =
          f2bf(o[df][r] * inv[r]);
}

// ---------------------------------------------------------------------------
extern "C" void kernel_launch(void* const* d_in, const int* in_sizes, int n_in,
                              void* d_out, int out_size, void* d_ws,
                              size_t ws_size, hipStream_t stream) {
  const float* x = (const float*)d_in[0];
  const float* ctx = (const float*)d_in[1];
  const float* q1_w = (const float*)d_in[2];
  const float* k1_w = (const float*)d_in[3];
  const float* v1_w = (const float*)d_in[4];
  const float* o1_w = (const float*)d_in[5];
  const float* o1_b = (const float*)d_in[6];
  const float* q2_w = (const float*)d_in[7];
  const float* k2_w = (const float*)d_in[8];
  const float* v2_w = (const float*)d_in[9];
  const float* o2_w = (const float*)d_in[10];
  const float* o2_b = (const float*)d_in[11];
  const float* ff_in_w = (const float*)d_in[12];
  const float* ff_in_b = (const float*)d_in[13];
  const float* ff_out_w = (const float*)d_in[14];
  const float* ff_out_b = (const float*)d_in[15];
  const float* ln1_g = (const float*)d_in[16];
  const float* ln1_b = (const float*)d_in[17];
  const float* ln2_g = (const float*)d_in[18];
  const float* ln2_b = (const float*)d_in[19];
  const float* ln3_g = (const float*)d_in[20];
  const float* ln3_b = (const float*)d_in[21];

  char* ws = (char*)d_ws;
  float* xr = (float*)(ws + 0);                    // 16.78 MB fp32 residual
  bf16_t* hb = (bf16_t*)(ws + 16777216);           // 8.39 MB LN output
  bf16_t* qb = (bf16_t*)(ws + 25165824);           // 8.39 MB
  bf16_t* kb = (bf16_t*)(ws + 33554432);           // 8.39 MB
  bf16_t* vb = (bf16_t*)(ws + 41943040);           // (unused; part of ffmid)
  bf16_t* ao = (bf16_t*)(ws + 50331648);           // 8.39 MB
  bf16_t* ffmid = qb;                              // aliases qb..ao (33.55 MB)
  bf16_t* ctxb = (bf16_t*)(ws + 58720256);         // 0.79 MB
  bf16_t* wts = (bf16_t*)(ws + 59506688);          // 11.01 MB bf16 weights^T
  bf16_t* vtg = (bf16_t*)(ws + 70516736);          // 8.39 MB V^T [512][8192]
  bf16_t* vtg2 = (bf16_t*)(ws + 78905344);         // 0.52 MB V^T [512][512]
  (void)vb;

  bf16_t* q1t = wts + 0;
  bf16_t* k1t = wts + 262144;
  bf16_t* v1t = wts + 524288;
  bf16_t* o1t = wts + 786432;
  bf16_t* q2t = wts + 1048576;
  bf16_t* k2t = wts + 1310720;
  bf16_t* v2t = wts + 1703936;
  bf16_t* o2t = wts + 2097152;
  bf16_t* ffint = wts + 2359296;
  bf16_t* ffoutt = wts + 4456448;

  // weight transposes fp32[K][N] -> bf16[N][K]
  wtrans_kernel<<<dim3(16, 16), 256, 0, stream>>>(q1_w, q1t, 512, 512);
  wtrans_kernel<<<dim3(16, 16), 256, 0, stream>>>(k1_w, k1t, 512, 512);
  wtrans_kernel<<<dim3(16, 16), 256, 0, stream>>>(v1_w, v1t, 512, 512);
  wtrans_kernel<<<dim3(16, 16), 256, 0, stream>>>(o1_w, o1t, 512, 512);
  wtrans_kernel<<<dim3(16, 16), 256, 0, stream>>>(q2_w, q2t, 512, 512);
  wtrans_kernel<<<dim3(24, 16), 256, 0, stream>>>(k2_w, k2t, 768, 512);
  wtrans_kernel<<<dim3(24, 16), 256, 0, stream>>>(v2_w, v2t, 768, 512);
  wtrans_kernel<<<dim3(16, 16), 256, 0, stream>>>(o2_w, o2t, 512, 512);
  wtrans_kernel<<<dim3(16, 128), 256, 0, stream>>>(ff_in_w, ffint, 512, 4096);
  wtrans_kernel<<<dim3(64, 16), 256, 0, stream>>>(ff_out_w, ffoutt, 2048, 512);
  cvt_kernel<<<384, 256, 0, stream>>>(ctx, ctxb);  // 2*256*768

  // ---- self-attention ----
  ln_kernel<<<2048, 256, 0, stream>>>(x, ln1_g, ln1_b, hb);
  gemm_kernel<128, 0><<<dim3(64, 4), 256, 0, stream>>>(
      hb, q1t, nullptr, nullptr, qb, 8192, 512, 512, 0, 512);
  gemm_kernel<128, 0><<<dim3(64, 4), 256, 0, stream>>>(
      hb, k1t, nullptr, nullptr, kb, 8192, 512, 512, 0, 512);
  // V^T = v1t[512x512K] @ hb^T  -> vtg[vdim][token], ldo = 8192
  gemm_kernel<128, 0><<<dim3(4, 64), 256, 0, stream>>>(
      v1t, hb, nullptr, nullptr, vtg, 512, 8192, 512, 0, 8192);
  attn_kernel<<<dim3(64, 8, 2), 256, 0, stream>>>(qb, kb, vtg, ao, 4096);
  gemm_kernel<128, 1><<<dim3(64, 4), 256, 0, stream>>>(
      ao, o1t, o1_b, x, xr, 8192, 512, 512, 0, 512);

  // ---- cross-attention ----
  ln_kernel<<<2048, 256, 0, stream>>>(xr, ln2_g, ln2_b, hb);
  gemm_kernel<128, 0><<<dim3(64, 4), 256, 0, stream>>>(
      hb, q2t, nullptr, nullptr, qb, 8192, 512, 512, 0, 512);
  gemm_kernel<128, 0><<<dim3(4, 4), 256, 0, stream>>>(
      ctxb, k2t, nullptr, nullptr, kb, 512, 512, 768, 0, 512);
  // V^T = v2t[512x768K] @ ctxb^T -> vtg2[vdim][b*256+tok], ldo = 512
  gemm_kernel<128, 0><<<dim3(4, 4), 256, 0, stream>>>(
      v2t, ctxb, nullptr, nullptr, vtg2, 512, 512, 768, 0, 512);
  attn_kernel<<<dim3(64, 8, 2), 256, 0, stream>>>(qb, kb, vtg2, ao, 256);
  gemm_kernel<128, 1><<<dim3(64, 4), 256, 0, stream>>>(
      ao, o2t, o2_b, xr, xr, 8192, 512, 512, 0, 512);

  // ---- GEGLU FF ----
  ln_kernel<<<2048, 256, 0, stream>>>(xr, ln3_g, ln3_b, hb);
  gemm_kernel<64, 2><<<dim3(64, 32), 256, 0, stream>>>(
      hb, ffint, ff_in_b, nullptr, ffmid, 8192, 2048, 512, 2048, 2048);
  gemm_kernel<128, 1><<<dim3(64, 4), 256, 0, stream>>>(
      ffmid, ffoutt, ff_out_b, xr, (float*)d_out, 8192, 512, 2048, 0, 512);
}

// Round 3
// 427.314 us; speedup vs baseline: 1.3853x; 1.1660x over previous
//
#include <hip/hip_runtime.h>
#include <hip/hip_bf16.h>
#include <cstdint>

// ---------------------------------------------------------------------------
// BasicTransformerBlock: LN -> self-attn -> LN -> cross-attn -> LN -> GEGLU FF
// B=2, N=4096, DIM=512, HEADS=8, D_HEAD=64, CTX: M=256, CD=768, FF_INNER=2048
// fp32 residual/LN, bf16 MFMA GEMMs + flash attention.
// R3: swapped QK^T (C[key][q]) -> lane-local softmax rows, defer-max rescale,
//     contiguous b64 P-repack writes.
// ---------------------------------------------------------------------------

typedef __bf16 bf16_t;
typedef __bf16 bf16x8 __attribute__((ext_vector_type(8)));
typedef __bf16 bf16x4 __attribute__((ext_vector_type(4)));
typedef float f32x4 __attribute__((ext_vector_type(4)));
typedef unsigned int u32x4 __attribute__((ext_vector_type(4)));

__device__ __forceinline__ bf16_t f2bf(float f) { return (bf16_t)f; }

__device__ __forceinline__ f32x4 mfma16(bf16x8 a, bf16x8 b, f32x4 c) {
  return __builtin_amdgcn_mfma_f32_16x16x32_bf16(a, b, c, 0, 0, 0);
}

__device__ __forceinline__ float gelu_exact(float x) {
  return 0.5f * x * (1.0f + erff(x * 0.70710678118654752f));
}

// ---------------------------------------------------------------------------
// LayerNorm: one wave per row of 512 fp32; writes bf16.
// ---------------------------------------------------------------------------
__global__ __launch_bounds__(256) void ln_kernel(const float* __restrict__ in,
                                                 const float* __restrict__ gw,
                                                 const float* __restrict__ bw,
                                                 bf16_t* __restrict__ out) {
  int w = threadIdx.x >> 6, l = threadIdx.x & 63;
  size_t row = (size_t)blockIdx.x * 4 + w;
  const float* p = in + row * 512 + l * 8;
  f32x4 va = *(const f32x4*)p;
  f32x4 vb = *(const f32x4*)(p + 4);
  float xs[8] = {va[0], va[1], va[2], va[3], vb[0], vb[1], vb[2], vb[3]};
  float s = 0.f;
#pragma unroll
  for (int j = 0; j < 8; j++) s += xs[j];
#pragma unroll
  for (int m = 1; m < 64; m <<= 1) s += __shfl_xor(s, m);
  float mu = s * (1.0f / 512.0f);
  float v = 0.f;
#pragma unroll
  for (int j = 0; j < 8; j++) { float d = xs[j] - mu; v += d * d; }
#pragma unroll
  for (int m = 1; m < 64; m <<= 1) v += __shfl_xor(v, m);
  float rstd = rsqrtf(v * (1.0f / 512.0f) + 1e-5f);
  f32x4 g0 = *(const f32x4*)(gw + l * 8);
  f32x4 g1 = *(const f32x4*)(gw + l * 8 + 4);
  f32x4 b0 = *(const f32x4*)(bw + l * 8);
  f32x4 b1 = *(const f32x4*)(bw + l * 8 + 4);
  bf16x8 o;
#pragma unroll
  for (int j = 0; j < 4; j++) o[j] = f2bf((xs[j] - mu) * rstd * g0[j] + b0[j]);
#pragma unroll
  for (int j = 0; j < 4; j++) o[4 + j] = f2bf((xs[4 + j] - mu) * rstd * g1[j] + b1[j]);
  *(bf16x8*)(out + row * 512 + l * 8) = o;
}

// ---------------------------------------------------------------------------
// Weight transpose+convert: W fp32 [K][N] -> Wt bf16 [N][K]
// ---------------------------------------------------------------------------
__global__ __launch_bounds__(256) void wtrans_kernel(const float* __restrict__ W,
                                                     bf16_t* __restrict__ Wt,
                                                     int K, int N) {
  __shared__ float t[32][33];
  int k0 = blockIdx.x * 32, n0 = blockIdx.y * 32;
#pragma unroll
  for (int i = 0; i < 4; i++) {
    int idx = threadIdx.x + i * 256;
    int kk = idx >> 5, nn = idx & 31;
    t[kk][nn] = W[(size_t)(k0 + kk) * N + n0 + nn];
  }
  __syncthreads();
#pragma unroll
  for (int i = 0; i < 4; i++) {
    int idx = threadIdx.x + i * 256;
    int nn = idx >> 5, kk = idx & 31;
    Wt[(size_t)(n0 + nn) * K + k0 + kk] = f2bf(t[kk][nn]);
  }
}

// fp32 -> bf16 elementwise (n multiple of 1024)
__global__ __launch_bounds__(256) void cvt_kernel(const float* __restrict__ in,
                                                  bf16_t* __restrict__ out) {
  int i = (blockIdx.x * 256 + threadIdx.x) * 4;
  f32x4 v = *(const f32x4*)(in + i);
  out[i + 0] = f2bf(v[0]);
  out[i + 1] = f2bf(v[1]);
  out[i + 2] = f2bf(v[2]);
  out[i + 3] = f2bf(v[3]);
}

// ---------------------------------------------------------------------------
// GEMM: C[M][N] = A[M][K](bf16) @ B (given as Bt bf16 [N][K]).
// BM=128, BK=32, 256 threads, 2x2 wave grid.
// EPI 0: write bf16 out.
// EPI 1: write fp32 out = acc + bias[col] + res[row*ldo+col].
// EPI 2 (BN=64): GEGLU: val=acc+bias[col], gate=acc2+bias[col+gateOff],
//                out bf16 = val * gelu(gate).
// ---------------------------------------------------------------------------
template <int BN, int EPI>
__global__ __launch_bounds__(256) void gemm_kernel(
    const bf16_t* __restrict__ A, const bf16_t* __restrict__ Bt,
    const float* __restrict__ bias, const float* __restrict__ res,
    void* __restrict__ outp, int M, int N, int K, int gateOff, int ldo) {
  constexpr int WN = BN / 2;
  constexpr int NF = WN / 16;
  constexpr int LDT = 48;
  __shared__ bf16_t Al[128][LDT];
  __shared__ bf16_t Bl[(EPI == 2 ? 2 * BN : BN)][LDT];

  int tid = threadIdx.x;
  int w = tid >> 6, l = tid & 63;
  int wr = w >> 1, wc = w & 1;
  int lg = l >> 4, lc = l & 15;
  int m0 = blockIdx.x * 128, n0 = blockIdx.y * BN;

  f32x4 acc[4][NF] = {};
  f32x4 acc2[4][NF] = {};

  int arow = tid >> 1, akc = (tid & 1) * 16;

  for (int k0 = 0; k0 < K; k0 += 32) {
    const bf16_t* asrc = A + (size_t)(m0 + arow) * K + k0 + akc;
    u32x4 a0 = *(const u32x4*)asrc;
    u32x4 a1 = *(const u32x4*)(asrc + 8);
    if (BN == 128) {
      const bf16_t* bsrc = Bt + (size_t)(n0 + arow) * K + k0 + akc;
      u32x4 bb0 = *(const u32x4*)bsrc;
      u32x4 bb1 = *(const u32x4*)(bsrc + 8);
      __syncthreads();
      *(u32x4*)&Al[arow][akc] = a0;
      *(u32x4*)&Al[arow][akc + 8] = a1;
      *(u32x4*)&Bl[arow][akc] = bb0;
      *(u32x4*)&Bl[arow][akc + 8] = bb1;
    } else {
      int brow = tid >> 2, bkc = (tid & 3) * 8;
      u32x4 bb0 = *(const u32x4*)(Bt + (size_t)(n0 + brow) * K + k0 + bkc);
      u32x4 bb1 = {};
      if (EPI == 2)
        bb1 = *(const u32x4*)(Bt + (size_t)(n0 + gateOff + brow) * K + k0 + bkc);
      __syncthreads();
      *(u32x4*)&Al[arow][akc] = a0;
      *(u32x4*)&Al[arow][akc + 8] = a1;
      *(u32x4*)&Bl[brow][bkc] = bb0;
      if (EPI == 2) *(u32x4*)&Bl[BN + brow][bkc] = bb1;
    }
    __syncthreads();

    bf16x8 af[4];
#pragma unroll
    for (int mi = 0; mi < 4; mi++)
      af[mi] = *(const bf16x8*)&Al[wr * 64 + mi * 16 + lc][lg * 8];
    bf16x8 bfr[NF];
#pragma unroll
    for (int ni = 0; ni < NF; ni++)
      bfr[ni] = *(const bf16x8*)&Bl[wc * WN + ni * 16 + lc][lg * 8];
#pragma unroll
    for (int mi = 0; mi < 4; mi++)
#pragma unroll
      for (int ni = 0; ni < NF; ni++)
        acc[mi][ni] = mfma16(af[mi], bfr[ni], acc[mi][ni]);
    if (EPI == 2) {
      bf16x8 bg[NF];
#pragma unroll
      for (int ni = 0; ni < NF; ni++)
        bg[ni] = *(const bf16x8*)&Bl[BN + wc * WN + ni * 16 + lc][lg * 8];
#pragma unroll
      for (int mi = 0; mi < 4; mi++)
#pragma unroll
        for (int ni = 0; ni < NF; ni++)
          acc2[mi][ni] = mfma16(af[mi], bg[ni], acc2[mi][ni]);
    }
    __syncthreads();
  }

#pragma unroll
  for (int mi = 0; mi < 4; mi++) {
#pragma unroll
    for (int ni = 0; ni < NF; ni++) {
#pragma unroll
      for (int r = 0; r < 4; r++) {
        int row = m0 + wr * 64 + mi * 16 + lg * 4 + r;
        int col = n0 + wc * WN + ni * 16 + lc;
        float v = acc[mi][ni][r];
        if (EPI == 0) {
          ((bf16_t*)outp)[(size_t)row * ldo + col] = f2bf(v);
        } else if (EPI == 1) {
          ((float*)outp)[(size_t)row * ldo + col] =
              v + bias[col] + res[(size_t)row * ldo + col];
        } else {
          float g = acc2[mi][ni][r] + bias[col + gateOff];
          float val = v + bias[col];
          ((bf16_t*)outp)[(size_t)row * ldo + col] = f2bf(val * gelu_exact(g));
        }
      }
    }
  }
}

// ---------------------------------------------------------------------------
// Flash attention v3. Block = 256 threads (4 waves); one (b, head, 64 q-rows)
// per block; each wave owns 16 q-rows. KV tiles of 64.
// Swapped QK^T: S^T = K @ Q^T -> C[key][q]; each lane holds the full 64-key
// P-row for q = lane&15 -> lane-local max, 2-shfl finish, defer-max rescale,
// contiguous b64 P-repack. Row-sums via ones-MFMA.
// Q,K layout: [B*tokens][512] bf16. V pre-transposed in global:
// Vt[vdim=h*64+d][B*Mkv tokens] (ldv = 2*Mkv).
// ---------------------------------------------------------------------------
__global__ __launch_bounds__(256) void attn_kernel(
    const bf16_t* __restrict__ Q, const bf16_t* __restrict__ Kb,
    const bf16_t* __restrict__ Vt, bf16_t* __restrict__ O, int Mkv) {
  __shared__ bf16_t Klds[64][72];
  __shared__ bf16_t Vlds[64][72];  // rows = d, cols = key
  __shared__ bf16_t Plds[4][16][72];  // per-wave: rows = q, cols = key

  int qt = blockIdx.x, head = blockIdx.y, b = blockIdx.z;
  int tid = threadIdx.x;
  int w = tid >> 6, l = tid & 63;
  int lg = l >> 4, lc = l & 15;
  int ldv = 2 * Mkv;

  // Q fragment as B-operand: lane lc holds q-row (w*16+lc), k = d
  size_t qtok = (size_t)b * 4096 + qt * 64 + w * 16 + lc;
  const bf16_t* qp = Q + qtok * 512 + head * 64;
  bf16x8 bq0 = *(const bf16x8*)(qp + lg * 8);
  bf16x8 bq1 = *(const bf16x8*)(qp + 32 + lg * 8);

  f32x4 o[4] = {};
  f32x4 zacc = {};        // running row-sums (rows = q = lg*4+r)
  float mrun = -1e30f;    // running max for q = lc (log2 domain)

  bf16x8 vones;
#pragma unroll
  for (int j = 0; j < 8; j++) vones[j] = f2bf(1.0f);

  int key0 = tid >> 2, dc0 = (tid & 3) * 16;
  const float SC = 0.125f * 1.44269504f;  // scale * log2(e)
  const bf16_t* kp = Kb + ((size_t)b * Mkv + key0) * 512 + head * 64 + dc0;
  const bf16_t* vp = Vt + (size_t)(head * 64 + key0) * ldv + b * Mkv + dc0;

  for (int t0 = 0; t0 < Mkv; t0 += 64, kp += 64 * 512, vp += 64) {
    bf16x8 kv0 = *(const bf16x8*)kp;
    bf16x8 kv1 = *(const bf16x8*)(kp + 8);
    bf16x8 vv0 = *(const bf16x8*)vp;
    bf16x8 vv1 = *(const bf16x8*)(vp + 8);
    __syncthreads();  // previous tile's LDS reads complete
    *(bf16x8*)&Klds[key0][dc0] = kv0;
    *(bf16x8*)&Klds[key0][dc0 + 8] = kv1;
    *(bf16x8*)&Vlds[key0][dc0] = vv0;  // row = d (key0 reused as d index)
    *(bf16x8*)&Vlds[key0][dc0 + 8] = vv1;
    __syncthreads();

    // S^T = K Q^T (C[key][q]), log2-scaled. Lane: q=lc, keys kg*16+lg*4+r.
    f32x4 s[4];
    __builtin_amdgcn_s_setprio(1);
#pragma unroll
    for (int kg = 0; kg < 4; kg++) {
      bf16x8 ak0 = *(const bf16x8*)&Klds[kg * 16 + lc][lg * 8];
      bf16x8 ak1 = *(const bf16x8*)&Klds[kg * 16 + lc][32 + lg * 8];
      f32x4 z = {};
      z = mfma16(ak0, bq0, z);
      z = mfma16(ak1, bq1, z);
      s[kg] = z * SC;
    }
    __builtin_amdgcn_s_setprio(0);

    // lane-local max over 16 vals + 2-shfl cross-group finish
    f32x4 t4 = s[0];
#pragma unroll
    for (int kg = 1; kg < 4; kg++) {
      t4[0] = fmaxf(t4[0], s[kg][0]);
      t4[1] = fmaxf(t4[1], s[kg][1]);
      t4[2] = fmaxf(t4[2], s[kg][2]);
      t4[3] = fmaxf(t4[3], s[kg][3]);
    }
    float tmax = fmaxf(fmaxf(t4[0], t4[1]), fmaxf(t4[2], t4[3]));
    tmax = fmaxf(tmax, __shfl_xor(tmax, 16));
    tmax = fmaxf(tmax, __shfl_xor(tmax, 32));

    // defer-max: only rescale when the tile max grows past threshold
    if (!__all(tmax <= mrun + 8.0f)) {
      float mnew = fmaxf(mrun, tmax);
      float resc = __builtin_amdgcn_exp2f(mrun - mnew);  // for q = lc
      mrun = mnew;
      float rr[4];
#pragma unroll
      for (int r = 0; r < 4; r++) rr[r] = __shfl(resc, lg * 4 + r);
#pragma unroll
      for (int df = 0; df < 4; df++)
#pragma unroll
        for (int r = 0; r < 4; r++) o[df][r] *= rr[r];
#pragma unroll
      for (int r = 0; r < 4; r++) zacc[r] *= rr[r];
    }

    // P = exp2(s - mrun); contiguous 4-key packs -> Plds[q][key]
#pragma unroll
    for (int kg = 0; kg < 4; kg++) {
      bf16x4 pv;
#pragma unroll
      for (int r = 0; r < 4; r++)
        pv[r] = f2bf(__builtin_amdgcn_exp2f(s[kg][r] - mrun));
      *(bf16x4*)&Plds[w][lc][kg * 16 + lg * 4] = pv;
    }

    bf16x8 pa0 = *(const bf16x8*)&Plds[w][lc][lg * 8];
    bf16x8 pa1 = *(const bf16x8*)&Plds[w][lc][32 + lg * 8];
    __builtin_amdgcn_s_setprio(1);
    zacc = mfma16(pa0, vones, zacc);  // row-sums on the matrix pipe
    zacc = mfma16(pa1, vones, zacc);
#pragma unroll
    for (int df = 0; df < 4; df++) {
      bf16x8 vb0 = *(const bf16x8*)&Vlds[df * 16 + lc][lg * 8];
      bf16x8 vb1 = *(const bf16x8*)&Vlds[df * 16 + lc][32 + lg * 8];
      o[df] = mfma16(pa0, vb0, o[df]);
      o[df] = mfma16(pa1, vb1, o[df]);
    }
    __builtin_amdgcn_s_setprio(0);
  }

  float inv[4];
#pragma unroll
  for (int r = 0; r < 4; r++) inv[r] = 1.0f / zacc[r];
  size_t obase = ((size_t)b * 4096 + qt * 64 + w * 16) * 512 + head * 64;
#pragma unroll
  for (int df = 0; df < 4; df++)
#pragma unroll
    for (int r = 0; r < 4; r++)
      O[obase + (size_t)(lg * 4 + r) * 512 + df * 16 + lc] =
          f2bf(o[df][r] * inv[r]);
}

// ---------------------------------------------------------------------------
extern "C" void kernel_launch(void* const* d_in, const int* in_sizes, int n_in,
                              void* d_out, int out_size, void* d_ws,
                              size_t ws_size, hipStream_t stream) {
  const float* x = (const float*)d_in[0];
  const float* ctx = (const float*)d_in[1];
  const float* q1_w = (const float*)d_in[2];
  const float* k1_w = (const float*)d_in[3];
  const float* v1_w = (const float*)d_in[4];
  const float* o1_w = (const float*)d_in[5];
  const float* o1_b = (const float*)d_in[6];
  const float* q2_w = (const float*)d_in[7];
  const float* k2_w = (const float*)d_in[8];
  const float* v2_w = (const float*)d_in[9];
  const float* o2_w = (const float*)d_in[10];
  const float* o2_b = (const float*)d_in[11];
  const float* ff_in_w = (const float*)d_in[12];
  const float* ff_in_b = (const float*)d_in[13];
  const float* ff_out_w = (const float*)d_in[14];
  const float* ff_out_b = (const float*)d_in[15];
  const float* ln1_g = (const float*)d_in[16];
  const float* ln1_b = (const float*)d_in[17];
  const float* ln2_g = (const float*)d_in[18];
  const float* ln2_b = (const float*)d_in[19];
  const float* ln3_g = (const float*)d_in[20];
  const float* ln3_b = (const float*)d_in[21];

  char* ws = (char*)d_ws;
  float* xr = (float*)(ws + 0);                    // 16.78 MB fp32 residual
  bf16_t* hb = (bf16_t*)(ws + 16777216);           // 8.39 MB LN output
  bf16_t* qb = (bf16_t*)(ws + 25165824);           // 8.39 MB
  bf16_t* kb = (bf16_t*)(ws + 33554432);           // 8.39 MB
  bf16_t* ao = (bf16_t*)(ws + 50331648);           // 8.39 MB
  bf16_t* ffmid = qb;                              // aliases qb.. (33.55 MB)
  bf16_t* ctxb = (bf16_t*)(ws + 58720256);         // 0.79 MB
  bf16_t* wts = (bf16_t*)(ws + 59506688);          // 11.01 MB bf16 weights^T
  bf16_t* vtg = (bf16_t*)(ws + 70516736);          // 8.39 MB V^T [512][8192]
  bf16_t* vtg2 = (bf16_t*)(ws + 78905344);         // 0.52 MB V^T [512][512]

  bf16_t* q1t = wts + 0;
  bf16_t* k1t = wts + 262144;
  bf16_t* v1t = wts + 524288;
  bf16_t* o1t = wts + 786432;
  bf16_t* q2t = wts + 1048576;
  bf16_t* k2t = wts + 1310720;
  bf16_t* v2t = wts + 1703936;
  bf16_t* o2t = wts + 2097152;
  bf16_t* ffint = wts + 2359296;
  bf16_t* ffoutt = wts + 4456448;

  // weight transposes fp32[K][N] -> bf16[N][K]
  wtrans_kernel<<<dim3(16, 16), 256, 0, stream>>>(q1_w, q1t, 512, 512);
  wtrans_kernel<<<dim3(16, 16), 256, 0, stream>>>(k1_w, k1t, 512, 512);
  wtrans_kernel<<<dim3(16, 16), 256, 0, stream>>>(v1_w, v1t, 512, 512);
  wtrans_kernel<<<dim3(16, 16), 256, 0, stream>>>(o1_w, o1t, 512, 512);
  wtrans_kernel<<<dim3(16, 16), 256, 0, stream>>>(q2_w, q2t, 512, 512);
  wtrans_kernel<<<dim3(24, 16), 256, 0, stream>>>(k2_w, k2t, 768, 512);
  wtrans_kernel<<<dim3(24, 16), 256, 0, stream>>>(v2_w, v2t, 768, 512);
  wtrans_kernel<<<dim3(16, 16), 256, 0, stream>>>(o2_w, o2t, 512, 512);
  wtrans_kernel<<<dim3(16, 128), 256, 0, stream>>>(ff_in_w, ffint, 512, 4096);
  wtrans_kernel<<<dim3(64, 16), 256, 0, stream>>>(ff_out_w, ffoutt, 2048, 512);
  cvt_kernel<<<384, 256, 0, stream>>>(ctx, ctxb);  // 2*256*768

  // ---- self-attention ----
  ln_kernel<<<2048, 256, 0, stream>>>(x, ln1_g, ln1_b, hb);
  gemm_kernel<128, 0><<<dim3(64, 4), 256, 0, stream>>>(
      hb, q1t, nullptr, nullptr, qb, 8192, 512, 512, 0, 512);
  gemm_kernel<128, 0><<<dim3(64, 4), 256, 0, stream>>>(
      hb, k1t, nullptr, nullptr, kb, 8192, 512, 512, 0, 512);
  // V^T = v1t[512x512K] @ hb^T  -> vtg[vdim][token], ldo = 8192
  gemm_kernel<128, 0><<<dim3(4, 64), 256, 0, stream>>>(
      v1t, hb, nullptr, nullptr, vtg, 512, 8192, 512, 0, 8192);
  attn_kernel<<<dim3(64, 8, 2), 256, 0, stream>>>(qb, kb, vtg, ao, 4096);
  gemm_kernel<128, 1><<<dim3(64, 4), 256, 0, stream>>>(
      ao, o1t, o1_b, x, xr, 8192, 512, 512, 0, 512);

  // ---- cross-attention ----
  ln_kernel<<<2048, 256, 0, stream>>>(xr, ln2_g, ln2_b, hb);
  gemm_kernel<128, 0><<<dim3(64, 4), 256, 0, stream>>>(
      hb, q2t, nullptr, nullptr, qb, 8192, 512, 512, 0, 512);
  gemm_kernel<128, 0><<<dim3(4, 4), 256, 0, stream>>>(
      ctxb, k2t, nullptr, nullptr, kb, 512, 512, 768, 0, 512);
  // V^T = v2t[512x768K] @ ctxb^T -> vtg2[vdim][b*256+tok], ldo = 512
  gemm_kernel<128, 0><<<dim3(4, 4), 256, 0, stream>>>(
      v2t, ctxb, nullptr, nullptr, vtg2, 512, 512, 768, 0, 512);
  attn_kernel<<<dim3(64, 8, 2), 256, 0, stream>>>(qb, kb, vtg2, ao, 256);
  gemm_kernel<128, 1><<<dim3(64, 4), 256, 0, stream>>>(
      ao, o2t, o2_b, xr, xr, 8192, 512, 512, 0, 512);

  // ---- GEGLU FF ----
  ln_kernel<<<2048, 256, 0, stream>>>(xr, ln3_g, ln3_b, hb);
  gemm_kernel<64, 2><<<dim3(64, 32), 256, 0, stream>>>(
      hb, ffint, ff_in_b, nullptr, ffmid, 8192, 2048, 512, 2048, 2048);
  gemm_kernel<128, 1><<<dim3(64, 4), 256, 0, stream>>>(
      ffmid, ffoutt, ff_out_b, xr, (float*)d_out, 8192, 512, 2048, 0, 512);
}

// Round 4
// 392.479 us; speedup vs baseline: 1.5082x; 1.0888x over previous
//
#include <hip/hip_runtime.h>
#include <hip/hip_bf16.h>
#include <cstdint>

// ---------------------------------------------------------------------------
// BasicTransformerBlock: LN -> self-attn -> LN -> cross-attn -> LN -> GEGLU FF
// B=2, N=4096, DIM=512, HEADS=8, D_HEAD=64, CTX: M=256, CD=768, FF_INNER=2048
// fp32 residual/LN, bf16 MFMA GEMMs + flash attention.
// R4: GEMM rebuilt on m97 recipe -- global_load_lds width=16 staging into
//     linear [128][32] double-buffered LDS, 2-phase pipeline (stage next ||
//     compute current, one barrier per K-step).
// ---------------------------------------------------------------------------

typedef __bf16 bf16_t;
typedef __bf16 bf16x8 __attribute__((ext_vector_type(8)));
typedef __bf16 bf16x4 __attribute__((ext_vector_type(4)));
typedef float f32x4 __attribute__((ext_vector_type(4)));
typedef unsigned int u32x4 __attribute__((ext_vector_type(4)));

__device__ __forceinline__ bf16_t f2bf(float f) { return (bf16_t)f; }

__device__ __forceinline__ f32x4 mfma16(bf16x8 a, bf16x8 b, f32x4 c) {
  return __builtin_amdgcn_mfma_f32_16x16x32_bf16(a, b, c, 0, 0, 0);
}

__device__ __forceinline__ float gelu_exact(float x) {
  return 0.5f * x * (1.0f + erff(x * 0.70710678118654752f));
}

// async global->LDS, 16B per lane; lds base must be wave-uniform (HW writes
// base + lane*16), global address is per-lane.
__device__ __forceinline__ void gload_lds16(const bf16_t* g, bf16_t* lds) {
  __builtin_amdgcn_global_load_lds(
      (const __attribute__((address_space(1))) unsigned int*)g,
      (__attribute__((address_space(3))) unsigned int*)lds, 16, 0, 0);
}

// ---------------------------------------------------------------------------
// LayerNorm: one wave per row of 512 fp32; writes bf16.
// ---------------------------------------------------------------------------
__global__ __launch_bounds__(256) void ln_kernel(const float* __restrict__ in,
                                                 const float* __restrict__ gw,
                                                 const float* __restrict__ bw,
                                                 bf16_t* __restrict__ out) {
  int w = threadIdx.x >> 6, l = threadIdx.x & 63;
  size_t row = (size_t)blockIdx.x * 4 + w;
  const float* p = in + row * 512 + l * 8;
  f32x4 va = *(const f32x4*)p;
  f32x4 vb = *(const f32x4*)(p + 4);
  float xs[8] = {va[0], va[1], va[2], va[3], vb[0], vb[1], vb[2], vb[3]};
  float s = 0.f;
#pragma unroll
  for (int j = 0; j < 8; j++) s += xs[j];
#pragma unroll
  for (int m = 1; m < 64; m <<= 1) s += __shfl_xor(s, m);
  float mu = s * (1.0f / 512.0f);
  float v = 0.f;
#pragma unroll
  for (int j = 0; j < 8; j++) { float d = xs[j] - mu; v += d * d; }
#pragma unroll
  for (int m = 1; m < 64; m <<= 1) v += __shfl_xor(v, m);
  float rstd = rsqrtf(v * (1.0f / 512.0f) + 1e-5f);
  f32x4 g0 = *(const f32x4*)(gw + l * 8);
  f32x4 g1 = *(const f32x4*)(gw + l * 8 + 4);
  f32x4 b0 = *(const f32x4*)(bw + l * 8);
  f32x4 b1 = *(const f32x4*)(bw + l * 8 + 4);
  bf16x8 o;
#pragma unroll
  for (int j = 0; j < 4; j++) o[j] = f2bf((xs[j] - mu) * rstd * g0[j] + b0[j]);
#pragma unroll
  for (int j = 0; j < 4; j++) o[4 + j] = f2bf((xs[4 + j] - mu) * rstd * g1[j] + b1[j]);
  *(bf16x8*)(out + row * 512 + l * 8) = o;
}

// ---------------------------------------------------------------------------
// Weight transpose+convert: W fp32 [K][N] -> Wt bf16 [N][K]
// ---------------------------------------------------------------------------
__global__ __launch_bounds__(256) void wtrans_kernel(const float* __restrict__ W,
                                                     bf16_t* __restrict__ Wt,
                                                     int K, int N) {
  __shared__ float t[32][33];
  int k0 = blockIdx.x * 32, n0 = blockIdx.y * 32;
#pragma unroll
  for (int i = 0; i < 4; i++) {
    int idx = threadIdx.x + i * 256;
    int kk = idx >> 5, nn = idx & 31;
    t[kk][nn] = W[(size_t)(k0 + kk) * N + n0 + nn];
  }
  __syncthreads();
#pragma unroll
  for (int i = 0; i < 4; i++) {
    int idx = threadIdx.x + i * 256;
    int nn = idx >> 5, kk = idx & 31;
    Wt[(size_t)(n0 + nn) * K + k0 + kk] = f2bf(t[kk][nn]);
  }
}

// fp32 -> bf16 elementwise (n multiple of 1024)
__global__ __launch_bounds__(256) void cvt_kernel(const float* __restrict__ in,
                                                  bf16_t* __restrict__ out) {
  int i = (blockIdx.x * 256 + threadIdx.x) * 4;
  f32x4 v = *(const f32x4*)(in + i);
  out[i + 0] = f2bf(v[0]);
  out[i + 1] = f2bf(v[1]);
  out[i + 2] = f2bf(v[2]);
  out[i + 3] = f2bf(v[3]);
}

// ---------------------------------------------------------------------------
// GEMM: C[M][N] = A[M][K](bf16) @ B (given as Bt bf16 [N][K]).
// BM=128, BK=32, 256 threads, 2x2 wave grid, m97-style global_load_lds
// staging into linear [128][32] double-buffered LDS, 2-phase pipeline.
// EPI 0: write bf16 out.
// EPI 1: write fp32 out = acc + bias[col] + res[row*ldo+col].
// EPI 2 (BN=64): GEGLU: val=acc+bias[col], gate=acc2+bias[col+gateOff],
//                out bf16 = val * gelu(gate). B tile rows 0-63 = val cols,
//                rows 64-127 = gate cols.
// ---------------------------------------------------------------------------
template <int BN, int EPI>
__global__ __launch_bounds__(256) void gemm_kernel(
    const bf16_t* __restrict__ A, const bf16_t* __restrict__ Bt,
    const float* __restrict__ bias, const float* __restrict__ res,
    void* __restrict__ outp, int M, int N, int K, int gateOff, int ldo) {
  constexpr int WN = BN / 2;
  constexpr int NF = WN / 16;
  __shared__ bf16_t Al[2][128][32];
  __shared__ bf16_t Bl[2][128][32];

  int tid = threadIdx.x;
  int w = tid >> 6, l = tid & 63;
  int wr = w >> 1, wc = w & 1;
  int lg = l >> 4, lc = l & 15;
  int m0 = blockIdx.x * 128, n0 = blockIdx.y * BN;

  f32x4 acc[4][NF] = {};
  f32x4 acc2[4][NF] = {};

  // staging: lane covers 16B at (srow, scol); issue1 adds +64 rows.
  int srow = tid >> 2, scol = (tid & 3) * 8;
  const bf16_t* aB0 = A + (size_t)(m0 + srow) * K + scol;
  const bf16_t* aB1 = aB0 + (size_t)64 * K;
  const bf16_t* bB0 = Bt + (size_t)(n0 + srow) * K + scol;
  const bf16_t* bB1 = (EPI == 2)
                          ? Bt + (size_t)(n0 + gateOff + srow) * K + scol
                          : bB0 + (size_t)64 * K;

  auto STAGE = [&](int buf, int k0) {
    gload_lds16(aB0 + k0, &Al[buf][w * 16][0]);
    gload_lds16(aB1 + k0, &Al[buf][64 + w * 16][0]);
    gload_lds16(bB0 + k0, &Bl[buf][w * 16][0]);
    gload_lds16(bB1 + k0, &Bl[buf][64 + w * 16][0]);
  };

  int nk = K / 32;
  int cur = 0;
  STAGE(0, 0);
  __syncthreads();  // vmcnt(0) drain + barrier: buf0 ready

  for (int t = 0; t < nk; ++t) {
    if (t + 1 < nk) STAGE(cur ^ 1, (t + 1) * 32);  // in flight during compute

    bf16x8 af[4];
#pragma unroll
    for (int mi = 0; mi < 4; mi++)
      af[mi] = *(const bf16x8*)&Al[cur][wr * 64 + mi * 16 + lc][lg * 8];
    bf16x8 bfr[NF];
#pragma unroll
    for (int ni = 0; ni < NF; ni++)
      bfr[ni] = *(const bf16x8*)&Bl[cur][(EPI == 2 ? wc * WN : wc * WN) + ni * 16 + lc][lg * 8];
#pragma unroll
    for (int mi = 0; mi < 4; mi++)
#pragma unroll
      for (int ni = 0; ni < NF; ni++)
        acc[mi][ni] = mfma16(af[mi], bfr[ni], acc[mi][ni]);
    if (EPI == 2) {
      bf16x8 bg[NF];
#pragma unroll
      for (int ni = 0; ni < NF; ni++)
        bg[ni] = *(const bf16x8*)&Bl[cur][64 + wc * WN + ni * 16 + lc][lg * 8];
#pragma unroll
      for (int mi = 0; mi < 4; mi++)
#pragma unroll
        for (int ni = 0; ni < NF; ni++)
          acc2[mi][ni] = mfma16(af[mi], bg[ni], acc2[mi][ni]);
    }
    __syncthreads();  // drains vmcnt (next tile landed) + read-write hazard
    cur ^= 1;
  }

#pragma unroll
  for (int mi = 0; mi < 4; mi++) {
#pragma unroll
    for (int ni = 0; ni < NF; ni++) {
#pragma unroll
      for (int r = 0; r < 4; r++) {
        int row = m0 + wr * 64 + mi * 16 + lg * 4 + r;
        int col = n0 + wc * WN + ni * 16 + lc;
        float v = acc[mi][ni][r];
        if (EPI == 0) {
          ((bf16_t*)outp)[(size_t)row * ldo + col] = f2bf(v);
        } else if (EPI == 1) {
          ((float*)outp)[(size_t)row * ldo + col] =
              v + bias[col] + res[(size_t)row * ldo + col];
        } else {
          float g = acc2[mi][ni][r] + bias[col + gateOff];
          float val = v + bias[col];
          ((bf16_t*)outp)[(size_t)row * ldo + col] = f2bf(val * gelu_exact(g));
        }
      }
    }
  }
}

// ---------------------------------------------------------------------------
// Flash attention v3 (unchanged from R3). Block = 256 threads (4 waves);
// one (b, head, 64 q-rows) per block; each wave owns 16 q-rows. KV tiles 64.
// Swapped QK^T: C[key][q]; lane-local softmax, defer-max, b64 P-repack,
// row-sums via ones-MFMA. V pre-transposed in global: Vt[vdim][token].
// ---------------------------------------------------------------------------
__global__ __launch_bounds__(256) void attn_kernel(
    const bf16_t* __restrict__ Q, const bf16_t* __restrict__ Kb,
    const bf16_t* __restrict__ Vt, bf16_t* __restrict__ O, int Mkv) {
  __shared__ bf16_t Klds[64][72];
  __shared__ bf16_t Vlds[64][72];
  __shared__ bf16_t Plds[4][16][72];

  int qt = blockIdx.x, head = blockIdx.y, b = blockIdx.z;
  int tid = threadIdx.x;
  int w = tid >> 6, l = tid & 63;
  int lg = l >> 4, lc = l & 15;
  int ldv = 2 * Mkv;

  size_t qtok = (size_t)b * 4096 + qt * 64 + w * 16 + lc;
  const bf16_t* qp = Q + qtok * 512 + head * 64;
  bf16x8 bq0 = *(const bf16x8*)(qp + lg * 8);
  bf16x8 bq1 = *(const bf16x8*)(qp + 32 + lg * 8);

  f32x4 o[4] = {};
  f32x4 zacc = {};
  float mrun = -1e30f;

  bf16x8 vones;
#pragma unroll
  for (int j = 0; j < 8; j++) vones[j] = f2bf(1.0f);

  int key0 = tid >> 2, dc0 = (tid & 3) * 16;
  const float SC = 0.125f * 1.44269504f;
  const bf16_t* kp = Kb + ((size_t)b * Mkv + key0) * 512 + head * 64 + dc0;
  const bf16_t* vp = Vt + (size_t)(head * 64 + key0) * ldv + b * Mkv + dc0;

  for (int t0 = 0; t0 < Mkv; t0 += 64, kp += 64 * 512, vp += 64) {
    bf16x8 kv0 = *(const bf16x8*)kp;
    bf16x8 kv1 = *(const bf16x8*)(kp + 8);
    bf16x8 vv0 = *(const bf16x8*)vp;
    bf16x8 vv1 = *(const bf16x8*)(vp + 8);
    __syncthreads();
    *(bf16x8*)&Klds[key0][dc0] = kv0;
    *(bf16x8*)&Klds[key0][dc0 + 8] = kv1;
    *(bf16x8*)&Vlds[key0][dc0] = vv0;
    *(bf16x8*)&Vlds[key0][dc0 + 8] = vv1;
    __syncthreads();

    f32x4 s[4];
    __builtin_amdgcn_s_setprio(1);
#pragma unroll
    for (int kg = 0; kg < 4; kg++) {
      bf16x8 ak0 = *(const bf16x8*)&Klds[kg * 16 + lc][lg * 8];
      bf16x8 ak1 = *(const bf16x8*)&Klds[kg * 16 + lc][32 + lg * 8];
      f32x4 z = {};
      z = mfma16(ak0, bq0, z);
      z = mfma16(ak1, bq1, z);
      s[kg] = z * SC;
    }
    __builtin_amdgcn_s_setprio(0);

    f32x4 t4 = s[0];
#pragma unroll
    for (int kg = 1; kg < 4; kg++) {
      t4[0] = fmaxf(t4[0], s[kg][0]);
      t4[1] = fmaxf(t4[1], s[kg][1]);
      t4[2] = fmaxf(t4[2], s[kg][2]);
      t4[3] = fmaxf(t4[3], s[kg][3]);
    }
    float tmax = fmaxf(fmaxf(t4[0], t4[1]), fmaxf(t4[2], t4[3]));
    tmax = fmaxf(tmax, __shfl_xor(tmax, 16));
    tmax = fmaxf(tmax, __shfl_xor(tmax, 32));

    if (!__all(tmax <= mrun + 8.0f)) {
      float mnew = fmaxf(mrun, tmax);
      float resc = __builtin_amdgcn_exp2f(mrun - mnew);
      mrun = mnew;
      float rr[4];
#pragma unroll
      for (int r = 0; r < 4; r++) rr[r] = __shfl(resc, lg * 4 + r);
#pragma unroll
      for (int df = 0; df < 4; df++)
#pragma unroll
        for (int r = 0; r < 4; r++) o[df][r] *= rr[r];
#pragma unroll
      for (int r = 0; r < 4; r++) zacc[r] *= rr[r];
    }

#pragma unroll
    for (int kg = 0; kg < 4; kg++) {
      bf16x4 pv;
#pragma unroll
      for (int r = 0; r < 4; r++)
        pv[r] = f2bf(__builtin_amdgcn_exp2f(s[kg][r] - mrun));
      *(bf16x4*)&Plds[w][lc][kg * 16 + lg * 4] = pv;
    }

    bf16x8 pa0 = *(const bf16x8*)&Plds[w][lc][lg * 8];
    bf16x8 pa1 = *(const bf16x8*)&Plds[w][lc][32 + lg * 8];
    __builtin_amdgcn_s_setprio(1);
    zacc = mfma16(pa0, vones, zacc);
    zacc = mfma16(pa1, vones, zacc);
#pragma unroll
    for (int df = 0; df < 4; df++) {
      bf16x8 vb0 = *(const bf16x8*)&Vlds[df * 16 + lc][lg * 8];
      bf16x8 vb1 = *(const bf16x8*)&Vlds[df * 16 + lc][32 + lg * 8];
      o[df] = mfma16(pa0, vb0, o[df]);
      o[df] = mfma16(pa1, vb1, o[df]);
    }
    __builtin_amdgcn_s_setprio(0);
  }

  float inv[4];
#pragma unroll
  for (int r = 0; r < 4; r++) inv[r] = 1.0f / zacc[r];
  size_t obase = ((size_t)b * 4096 + qt * 64 + w * 16) * 512 + head * 64;
#pragma unroll
  for (int df = 0; df < 4; df++)
#pragma unroll
    for (int r = 0; r < 4; r++)
      O[obase + (size_t)(lg * 4 + r) * 512 + df * 16 + lc] =
          f2bf(o[df][r] * inv[r]);
}

// ---------------------------------------------------------------------------
extern "C" void kernel_launch(void* const* d_in, const int* in_sizes, int n_in,
                              void* d_out, int out_size, void* d_ws,
                              size_t ws_size, hipStream_t stream) {
  const float* x = (const float*)d_in[0];
  const float* ctx = (const float*)d_in[1];
  const float* q1_w = (const float*)d_in[2];
  const float* k1_w = (const float*)d_in[3];
  const float* v1_w = (const float*)d_in[4];
  const float* o1_w = (const float*)d_in[5];
  const float* o1_b = (const float*)d_in[6];
  const float* q2_w = (const float*)d_in[7];
  const float* k2_w = (const float*)d_in[8];
  const float* v2_w = (const float*)d_in[9];
  const float* o2_w = (const float*)d_in[10];
  const float* o2_b = (const float*)d_in[11];
  const float* ff_in_w = (const float*)d_in[12];
  const float* ff_in_b = (const float*)d_in[13];
  const float* ff_out_w = (const float*)d_in[14];
  const float* ff_out_b = (const float*)d_in[15];
  const float* ln1_g = (const float*)d_in[16];
  const float* ln1_b = (const float*)d_in[17];
  const float* ln2_g = (const float*)d_in[18];
  const float* ln2_b = (const float*)d_in[19];
  const float* ln3_g = (const float*)d_in[20];
  const float* ln3_b = (const float*)d_in[21];

  char* ws = (char*)d_ws;
  float* xr = (float*)(ws + 0);                    // 16.78 MB fp32 residual
  bf16_t* hb = (bf16_t*)(ws + 16777216);           // 8.39 MB LN output
  bf16_t* qb = (bf16_t*)(ws + 25165824);           // 8.39 MB
  bf16_t* kb = (bf16_t*)(ws + 33554432);           // 8.39 MB
  bf16_t* ao = (bf16_t*)(ws + 50331648);           // 8.39 MB
  bf16_t* ffmid = qb;                              // aliases qb.. (33.55 MB)
  bf16_t* ctxb = (bf16_t*)(ws + 58720256);         // 0.79 MB
  bf16_t* wts = (bf16_t*)(ws + 59506688);          // 11.01 MB bf16 weights^T
  bf16_t* vtg = (bf16_t*)(ws + 70516736);          // 8.39 MB V^T [512][8192]
  bf16_t* vtg2 = (bf16_t*)(ws + 78905344);         // 0.52 MB V^T [512][512]

  bf16_t* q1t = wts + 0;
  bf16_t* k1t = wts + 262144;
  bf16_t* v1t = wts + 524288;
  bf16_t* o1t = wts + 786432;
  bf16_t* q2t = wts + 1048576;
  bf16_t* k2t = wts + 1310720;
  bf16_t* v2t = wts + 1703936;
  bf16_t* o2t = wts + 2097152;
  bf16_t* ffint = wts + 2359296;
  bf16_t* ffoutt = wts + 4456448;

  // weight transposes fp32[K][N] -> bf16[N][K]
  wtrans_kernel<<<dim3(16, 16), 256, 0, stream>>>(q1_w, q1t, 512, 512);
  wtrans_kernel<<<dim3(16, 16), 256, 0, stream>>>(k1_w, k1t, 512, 512);
  wtrans_kernel<<<dim3(16, 16), 256, 0, stream>>>(v1_w, v1t, 512, 512);
  wtrans_kernel<<<dim3(16, 16), 256, 0, stream>>>(o1_w, o1t, 512, 512);
  wtrans_kernel<<<dim3(16, 16), 256, 0, stream>>>(q2_w, q2t, 512, 512);
  wtrans_kernel<<<dim3(24, 16), 256, 0, stream>>>(k2_w, k2t, 768, 512);
  wtrans_kernel<<<dim3(24, 16), 256, 0, stream>>>(v2_w, v2t, 768, 512);
  wtrans_kernel<<<dim3(16, 16), 256, 0, stream>>>(o2_w, o2t, 512, 512);
  wtrans_kernel<<<dim3(16, 128), 256, 0, stream>>>(ff_in_w, ffint, 512, 4096);
  wtrans_kernel<<<dim3(64, 16), 256, 0, stream>>>(ff_out_w, ffoutt, 2048, 512);
  cvt_kernel<<<384, 256, 0, stream>>>(ctx, ctxb);  // 2*256*768

  // ---- self-attention ----
  ln_kernel<<<2048, 256, 0, stream>>>(x, ln1_g, ln1_b, hb);
  gemm_kernel<128, 0><<<dim3(64, 4), 256, 0, stream>>>(
      hb, q1t, nullptr, nullptr, qb, 8192, 512, 512, 0, 512);
  gemm_kernel<128, 0><<<dim3(64, 4), 256, 0, stream>>>(
      hb, k1t, nullptr, nullptr, kb, 8192, 512, 512, 0, 512);
  // V^T = v1t[512x512K] @ hb^T  -> vtg[vdim][token], ldo = 8192
  gemm_kernel<128, 0><<<dim3(4, 64), 256, 0, stream>>>(
      v1t, hb, nullptr, nullptr, vtg, 512, 8192, 512, 0, 8192);
  attn_kernel<<<dim3(64, 8, 2), 256, 0, stream>>>(qb, kb, vtg, ao, 4096);
  gemm_kernel<128, 1><<<dim3(64, 4), 256, 0, stream>>>(
      ao, o1t, o1_b, x, xr, 8192, 512, 512, 0, 512);

  // ---- cross-attention ----
  ln_kernel<<<2048, 256, 0, stream>>>(xr, ln2_g, ln2_b, hb);
  gemm_kernel<128, 0><<<dim3(64, 4), 256, 0, stream>>>(
      hb, q2t, nullptr, nullptr, qb, 8192, 512, 512, 0, 512);
  gemm_kernel<128, 0><<<dim3(4, 4), 256, 0, stream>>>(
      ctxb, k2t, nullptr, nullptr, kb, 512, 512, 768, 0, 512);
  // V^T = v2t[512x768K] @ ctxb^T -> vtg2[vdim][b*256+tok], ldo = 512
  gemm_kernel<128, 0><<<dim3(4, 4), 256, 0, stream>>>(
      v2t, ctxb, nullptr, nullptr, vtg2, 512, 512, 768, 0, 512);
  attn_kernel<<<dim3(64, 8, 2), 256, 0, stream>>>(qb, kb, vtg2, ao, 256);
  gemm_kernel<128, 1><<<dim3(64, 4), 256, 0, stream>>>(
      ao, o2t, o2_b, xr, xr, 8192, 512, 512, 0, 512);

  // ---- GEGLU FF ----
  ln_kernel<<<2048, 256, 0, stream>>>(xr, ln3_g, ln3_b, hb);
  gemm_kernel<64, 2><<<dim3(64, 32), 256, 0, stream>>>(
      hb, ffint, ff_in_b, nullptr, ffmid, 8192, 2048, 512, 2048, 2048);
  gemm_kernel<128, 1><<<dim3(64, 4), 256, 0, stream>>>(
      ffmid, ffoutt, ff_out_b, xr, (float*)d_out, 8192, 512, 2048, 0, 512);
}

// Round 5
// 365.029 us; speedup vs baseline: 1.6216x; 1.0752x over previous
//
#include <hip/hip_runtime.h>
#include <hip/hip_bf16.h>
#include <cstdint>

// ---------------------------------------------------------------------------
// BasicTransformerBlock: LN -> self-attn -> LN -> cross-attn -> LN -> GEGLU FF
// B=2, N=4096, DIM=512, HEADS=8, D_HEAD=64, CTX: M=256, CD=768, FF_INNER=2048
// fp32 residual/LN, bf16 MFMA GEMMs + flash attention.
// R5: GEMM occupancy fixes -- fused Q|K projection (N=1024), BM=64 tile
//     variant for N=512 shapes (2 blocks/CU instead of 1). Attn: T14
//     prefetch (next K/V tile global loads issued under current compute).
// ---------------------------------------------------------------------------

typedef __bf16 bf16_t;
typedef __bf16 bf16x8 __attribute__((ext_vector_type(8)));
typedef __bf16 bf16x4 __attribute__((ext_vector_type(4)));
typedef float f32x4 __attribute__((ext_vector_type(4)));
typedef unsigned int u32x4 __attribute__((ext_vector_type(4)));

__device__ __forceinline__ bf16_t f2bf(float f) { return (bf16_t)f; }

__device__ __forceinline__ f32x4 mfma16(bf16x8 a, bf16x8 b, f32x4 c) {
  return __builtin_amdgcn_mfma_f32_16x16x32_bf16(a, b, c, 0, 0, 0);
}

__device__ __forceinline__ float gelu_exact(float x) {
  return 0.5f * x * (1.0f + erff(x * 0.70710678118654752f));
}

// async global->LDS, 16B per lane; lds base must be wave-uniform (HW writes
// base + lane*16), global address is per-lane.
__device__ __forceinline__ void gload_lds16(const bf16_t* g, bf16_t* lds) {
  __builtin_amdgcn_global_load_lds(
      (const __attribute__((address_space(1))) unsigned int*)g,
      (__attribute__((address_space(3))) unsigned int*)lds, 16, 0, 0);
}

// ---------------------------------------------------------------------------
// LayerNorm: one wave per row of 512 fp32; writes bf16.
// ---------------------------------------------------------------------------
__global__ __launch_bounds__(256) void ln_kernel(const float* __restrict__ in,
                                                 const float* __restrict__ gw,
                                                 const float* __restrict__ bw,
                                                 bf16_t* __restrict__ out) {
  int w = threadIdx.x >> 6, l = threadIdx.x & 63;
  size_t row = (size_t)blockIdx.x * 4 + w;
  const float* p = in + row * 512 + l * 8;
  f32x4 va = *(const f32x4*)p;
  f32x4 vb = *(const f32x4*)(p + 4);
  float xs[8] = {va[0], va[1], va[2], va[3], vb[0], vb[1], vb[2], vb[3]};
  float s = 0.f;
#pragma unroll
  for (int j = 0; j < 8; j++) s += xs[j];
#pragma unroll
  for (int m = 1; m < 64; m <<= 1) s += __shfl_xor(s, m);
  float mu = s * (1.0f / 512.0f);
  float v = 0.f;
#pragma unroll
  for (int j = 0; j < 8; j++) { float d = xs[j] - mu; v += d * d; }
#pragma unroll
  for (int m = 1; m < 64; m <<= 1) v += __shfl_xor(v, m);
  float rstd = rsqrtf(v * (1.0f / 512.0f) + 1e-5f);
  f32x4 g0 = *(const f32x4*)(gw + l * 8);
  f32x4 g1 = *(const f32x4*)(gw + l * 8 + 4);
  f32x4 b0 = *(const f32x4*)(bw + l * 8);
  f32x4 b1 = *(const f32x4*)(bw + l * 8 + 4);
  bf16x8 o;
#pragma unroll
  for (int j = 0; j < 4; j++) o[j] = f2bf((xs[j] - mu) * rstd * g0[j] + b0[j]);
#pragma unroll
  for (int j = 0; j < 4; j++) o[4 + j] = f2bf((xs[4 + j] - mu) * rstd * g1[j] + b1[j]);
  *(bf16x8*)(out + row * 512 + l * 8) = o;
}

// ---------------------------------------------------------------------------
// Weight transpose+convert: W fp32 [K][N] -> Wt bf16 [N][K]
// ---------------------------------------------------------------------------
__global__ __launch_bounds__(256) void wtrans_kernel(const float* __restrict__ W,
                                                     bf16_t* __restrict__ Wt,
                                                     int K, int N) {
  __shared__ float t[32][33];
  int k0 = blockIdx.x * 32, n0 = blockIdx.y * 32;
#pragma unroll
  for (int i = 0; i < 4; i++) {
    int idx = threadIdx.x + i * 256;
    int kk = idx >> 5, nn = idx & 31;
    t[kk][nn] = W[(size_t)(k0 + kk) * N + n0 + nn];
  }
  __syncthreads();
#pragma unroll
  for (int i = 0; i < 4; i++) {
    int idx = threadIdx.x + i * 256;
    int nn = idx >> 5, kk = idx & 31;
    Wt[(size_t)(n0 + nn) * K + k0 + kk] = f2bf(t[kk][nn]);
  }
}

// fp32 -> bf16 elementwise (n multiple of 1024)
__global__ __launch_bounds__(256) void cvt_kernel(const float* __restrict__ in,
                                                  bf16_t* __restrict__ out) {
  int i = (blockIdx.x * 256 + threadIdx.x) * 4;
  f32x4 v = *(const f32x4*)(in + i);
  out[i + 0] = f2bf(v[0]);
  out[i + 1] = f2bf(v[1]);
  out[i + 2] = f2bf(v[2]);
  out[i + 3] = f2bf(v[3]);
}

// ---------------------------------------------------------------------------
// GEMM: C[M][N] = A[M][K](bf16) @ B (given as Bt bf16 [N][K]).
// Template: BM in {64,128}, BN in {64,128}. 256 threads, 2x2 wave grid,
// global_load_lds width=16 staging, linear double-buffered LDS, 2-phase.
// EPI 0: write bf16 out.
// EPI 1: write fp32 out = acc + bias[col] + res[row*ldo+col].
// EPI 2 (BN=64): GEGLU: val=acc+bias[col], gate=acc2+bias[col+gateOff],
//                out bf16 = val * gelu(gate). B rows 0..63 val, 64..127 gate.
// ---------------------------------------------------------------------------
template <int BM, int BN, int EPI>
__global__ __launch_bounds__(256) void gemm_kernel(
    const bf16_t* __restrict__ A, const bf16_t* __restrict__ Bt,
    const float* __restrict__ bias, const float* __restrict__ res,
    void* __restrict__ outp, int M, int N, int K, int gateOff, int ldo) {
  constexpr int WR = BM / 2;
  constexpr int WN = BN / 2;
  constexpr int MF = WR / 16;
  constexpr int NF = WN / 16;
  constexpr int ABLK = BM / 64;
  constexpr int BROWS = (EPI == 2) ? 2 * BN : BN;
  constexpr int BBLK = BROWS / 64;
  __shared__ bf16_t Al[2][BM][32];
  __shared__ bf16_t Bl[2][BROWS][32];

  int tid = threadIdx.x;
  int w = tid >> 6, l = tid & 63;
  int wr = w >> 1, wc = w & 1;
  int lg = l >> 4, lc = l & 15;
  int m0 = blockIdx.x * BM, n0 = blockIdx.y * BN;

  f32x4 acc[MF][NF] = {};
  f32x4 acc2[MF][NF] = {};

  // staging: each lane covers 16B at (srow, scol) within a 64-row block.
  int srow = tid >> 2, scol = (tid & 3) * 8;
  const bf16_t* aP[ABLK];
#pragma unroll
  for (int i = 0; i < ABLK; i++)
    aP[i] = A + (size_t)(m0 + i * 64 + srow) * K + scol;
  const bf16_t* bP[BBLK];
  if (EPI == 2) {
    bP[0] = Bt + (size_t)(n0 + srow) * K + scol;
    bP[1] = Bt + (size_t)(n0 + gateOff + srow) * K + scol;
  } else {
#pragma unroll
    for (int i = 0; i < BBLK; i++)
      bP[i] = Bt + (size_t)(n0 + i * 64 + srow) * K + scol;
  }

  auto STAGE = [&](int buf, int k0) {
#pragma unroll
    for (int i = 0; i < ABLK; i++)
      gload_lds16(aP[i] + k0, &Al[buf][i * 64 + w * 16][0]);
#pragma unroll
    for (int i = 0; i < BBLK; i++)
      gload_lds16(bP[i] + k0, &Bl[buf][i * 64 + w * 16][0]);
  };

  int nk = K / 32;
  int cur = 0;
  STAGE(0, 0);
  __syncthreads();  // vmcnt(0) drain + barrier: buf0 ready

  for (int t = 0; t < nk; ++t) {
    if (t + 1 < nk) STAGE(cur ^ 1, (t + 1) * 32);  // in flight during compute

    bf16x8 af[MF];
#pragma unroll
    for (int mi = 0; mi < MF; mi++)
      af[mi] = *(const bf16x8*)&Al[cur][wr * WR + mi * 16 + lc][lg * 8];
    bf16x8 bfr[NF];
#pragma unroll
    for (int ni = 0; ni < NF; ni++)
      bfr[ni] = *(const bf16x8*)&Bl[cur][wc * WN + ni * 16 + lc][lg * 8];
#pragma unroll
    for (int mi = 0; mi < MF; mi++)
#pragma unroll
      for (int ni = 0; ni < NF; ni++)
        acc[mi][ni] = mfma16(af[mi], bfr[ni], acc[mi][ni]);
    if (EPI == 2) {
      bf16x8 bg[NF];
#pragma unroll
      for (int ni = 0; ni < NF; ni++)
        bg[ni] = *(const bf16x8*)&Bl[cur][BN + wc * WN + ni * 16 + lc][lg * 8];
#pragma unroll
      for (int mi = 0; mi < MF; mi++)
#pragma unroll
        for (int ni = 0; ni < NF; ni++)
          acc2[mi][ni] = mfma16(af[mi], bg[ni], acc2[mi][ni]);
    }
    __syncthreads();  // next tile landed + read-write hazard
    cur ^= 1;
  }

#pragma unroll
  for (int mi = 0; mi < MF; mi++) {
#pragma unroll
    for (int ni = 0; ni < NF; ni++) {
#pragma unroll
      for (int r = 0; r < 4; r++) {
        int row = m0 + wr * WR + mi * 16 + lg * 4 + r;
        int col = n0 + wc * WN + ni * 16 + lc;
        float v = acc[mi][ni][r];
        if (EPI == 0) {
          ((bf16_t*)outp)[(size_t)row * ldo + col] = f2bf(v);
        } else if (EPI == 1) {
          ((float*)outp)[(size_t)row * ldo + col] =
              v + bias[col] + res[(size_t)row * ldo + col];
        } else {
          float g = acc2[mi][ni][r] + bias[col + gateOff];
          float val = v + bias[col];
          ((bf16_t*)outp)[(size_t)row * ldo + col] = f2bf(val * gelu_exact(g));
        }
      }
    }
  }
}

// ---------------------------------------------------------------------------
// Flash attention. Block = 256 threads (4 waves); one (b, head, 64 q-rows)
// per block; each wave owns 16 q-rows. KV tiles 64. Swapped QK^T: C[key][q];
// lane-local softmax, defer-max, b64 P-repack, row-sums via ones-MFMA.
// R5: T14 prefetch -- next tile's K/V global loads issued under compute.
// Q rows stride ldq (fused QK buffer), K rows stride ldk.
// V pre-transposed in global: Vt[vdim][token], ldv = 2*Mkv.
// ---------------------------------------------------------------------------
__global__ __launch_bounds__(256) void attn_kernel(
    const bf16_t* __restrict__ Q, int ldq, const bf16_t* __restrict__ Kb,
    int ldk, const bf16_t* __restrict__ Vt, bf16_t* __restrict__ O, int Mkv) {
  __shared__ bf16_t Klds[64][72];
  __shared__ bf16_t Vlds[64][72];
  __shared__ bf16_t Plds[4][16][72];

  int qt = blockIdx.x, head = blockIdx.y, b = blockIdx.z;
  int tid = threadIdx.x;
  int w = tid >> 6, l = tid & 63;
  int lg = l >> 4, lc = l & 15;
  int ldv = 2 * Mkv;

  size_t qtok = (size_t)b * 4096 + qt * 64 + w * 16 + lc;
  const bf16_t* qp = Q + qtok * ldq + head * 64;
  bf16x8 bq0 = *(const bf16x8*)(qp + lg * 8);
  bf16x8 bq1 = *(const bf16x8*)(qp + 32 + lg * 8);

  f32x4 o[4] = {};
  f32x4 zacc = {};
  float mrun = -1e30f;

  bf16x8 vones;
#pragma unroll
  for (int j = 0; j < 8; j++) vones[j] = f2bf(1.0f);

  int key0 = tid >> 2, dc0 = (tid & 3) * 16;
  const float SC = 0.125f * 1.44269504f;
  const bf16_t* kp = Kb + ((size_t)b * Mkv + key0) * ldk + head * 64 + dc0;
  const bf16_t* vp = Vt + (size_t)(head * 64 + key0) * ldv + b * Mkv + dc0;

  // prefetch tile 0
  bf16x8 kc0 = *(const bf16x8*)kp, kc1 = *(const bf16x8*)(kp + 8);
  bf16x8 vc0 = *(const bf16x8*)vp, vc1 = *(const bf16x8*)(vp + 8);

  for (int t0 = 0; t0 < Mkv; t0 += 64) {
    __syncthreads();  // previous tile's LDS reads complete
    *(bf16x8*)&Klds[key0][dc0] = kc0;
    *(bf16x8*)&Klds[key0][dc0 + 8] = kc1;
    *(bf16x8*)&Vlds[key0][dc0] = vc0;
    *(bf16x8*)&Vlds[key0][dc0 + 8] = vc1;
    __syncthreads();

    if (t0 + 64 < Mkv) {  // issue next-tile loads; land during compute
      kp += (size_t)64 * ldk;
      vp += 64;
      kc0 = *(const bf16x8*)kp;
      kc1 = *(const bf16x8*)(kp + 8);
      vc0 = *(const bf16x8*)vp;
      vc1 = *(const bf16x8*)(vp + 8);
    }

    f32x4 s[4];
    __builtin_amdgcn_s_setprio(1);
#pragma unroll
    for (int kg = 0; kg < 4; kg++) {
      bf16x8 ak0 = *(const bf16x8*)&Klds[kg * 16 + lc][lg * 8];
      bf16x8 ak1 = *(const bf16x8*)&Klds[kg * 16 + lc][32 + lg * 8];
      f32x4 z = {};
      z = mfma16(ak0, bq0, z);
      z = mfma16(ak1, bq1, z);
      s[kg] = z * SC;
    }
    __builtin_amdgcn_s_setprio(0);

    f32x4 t4 = s[0];
#pragma unroll
    for (int kg = 1; kg < 4; kg++) {
      t4[0] = fmaxf(t4[0], s[kg][0]);
      t4[1] = fmaxf(t4[1], s[kg][1]);
      t4[2] = fmaxf(t4[2], s[kg][2]);
      t4[3] = fmaxf(t4[3], s[kg][3]);
    }
    float tmax = fmaxf(fmaxf(t4[0], t4[1]), fmaxf(t4[2], t4[3]));
    tmax = fmaxf(tmax, __shfl_xor(tmax, 16));
    tmax = fmaxf(tmax, __shfl_xor(tmax, 32));

    if (!__all(tmax <= mrun + 8.0f)) {
      float mnew = fmaxf(mrun, tmax);
      float resc = __builtin_amdgcn_exp2f(mrun - mnew);
      mrun = mnew;
      float rr[4];
#pragma unroll
      for (int r = 0; r < 4; r++) rr[r] = __shfl(resc, lg * 4 + r);
#pragma unroll
      for (int df = 0; df < 4; df++)
#pragma unroll
        for (int r = 0; r < 4; r++) o[df][r] *= rr[r];
#pragma unroll
      for (int r = 0; r < 4; r++) zacc[r] *= rr[r];
    }

#pragma unroll
    for (int kg = 0; kg < 4; kg++) {
      bf16x4 pv;
#pragma unroll
      for (int r = 0; r < 4; r++)
        pv[r] = f2bf(__builtin_amdgcn_exp2f(s[kg][r] - mrun));
      *(bf16x4*)&Plds[w][lc][kg * 16 + lg * 4] = pv;
    }

    bf16x8 pa0 = *(const bf16x8*)&Plds[w][lc][lg * 8];
    bf16x8 pa1 = *(const bf16x8*)&Plds[w][lc][32 + lg * 8];
    __builtin_amdgcn_s_setprio(1);
    zacc = mfma16(pa0, vones, zacc);
    zacc = mfma16(pa1, vones, zacc);
#pragma unroll
    for (int df = 0; df < 4; df++) {
      bf16x8 vb0 = *(const bf16x8*)&Vlds[df * 16 + lc][lg * 8];
      bf16x8 vb1 = *(const bf16x8*)&Vlds[df * 16 + lc][32 + lg * 8];
      o[df] = mfma16(pa0, vb0, o[df]);
      o[df] = mfma16(pa1, vb1, o[df]);
    }
    __builtin_amdgcn_s_setprio(0);
  }

  float inv[4];
#pragma unroll
  for (int r = 0; r < 4; r++) inv[r] = 1.0f / zacc[r];
  size_t obase = ((size_t)b * 4096 + qt * 64 + w * 16) * 512 + head * 64;
#pragma unroll
  for (int df = 0; df < 4; df++)
#pragma unroll
    for (int r = 0; r < 4; r++)
      O[obase + (size_t)(lg * 4 + r) * 512 + df * 16 + lc] =
          f2bf(o[df][r] * inv[r]);
}

// ---------------------------------------------------------------------------
extern "C" void kernel_launch(void* const* d_in, const int* in_sizes, int n_in,
                              void* d_out, int out_size, void* d_ws,
                              size_t ws_size, hipStream_t stream) {
  const float* x = (const float*)d_in[0];
  const float* ctx = (const float*)d_in[1];
  const float* q1_w = (const float*)d_in[2];
  const float* k1_w = (const float*)d_in[3];
  const float* v1_w = (const float*)d_in[4];
  const float* o1_w = (const float*)d_in[5];
  const float* o1_b = (const float*)d_in[6];
  const float* q2_w = (const float*)d_in[7];
  const float* k2_w = (const float*)d_in[8];
  const float* v2_w = (const float*)d_in[9];
  const float* o2_w = (const float*)d_in[10];
  const float* o2_b = (const float*)d_in[11];
  const float* ff_in_w = (const float*)d_in[12];
  const float* ff_in_b = (const float*)d_in[13];
  const float* ff_out_w = (const float*)d_in[14];
  const float* ff_out_b = (const float*)d_in[15];
  const float* ln1_g = (const float*)d_in[16];
  const float* ln1_b = (const float*)d_in[17];
  const float* ln2_g = (const float*)d_in[18];
  const float* ln2_b = (const float*)d_in[19];
  const float* ln3_g = (const float*)d_in[20];
  const float* ln3_b = (const float*)d_in[21];

  char* ws = (char*)d_ws;
  float* xr = (float*)(ws + 0);                    // 16.78 MB fp32 residual
  bf16_t* hb = (bf16_t*)(ws + 16777216);           // 8.39 MB LN output
  bf16_t* qkb = (bf16_t*)(ws + 25165824);          // 16.78 MB [8192][1024]
  bf16_t* ao = (bf16_t*)(ws + 41943040);           // 8.39 MB
  bf16_t* ffmid = qkb;                             // alias qkb+ao (33.55 MB)
  bf16_t* kb = (bf16_t*)(ws + 50331648);           // 0.52 MB cross K
  bf16_t* vtg2 = (bf16_t*)(ws + 50855936);         // 0.52 MB cross V^T
  bf16_t* ctxb = (bf16_t*)(ws + 51380224);         // 0.79 MB
  bf16_t* wts = (bf16_t*)(ws + 58720256);          // 11.01 MB bf16 weights^T
  bf16_t* vtg = (bf16_t*)(ws + 69730304);          // 8.39 MB V^T [512][8192]

  bf16_t* q1t = wts + 0;        // q1t,k1t adjacent -> fused Q|K weight [1024][512]
  bf16_t* k1t = wts + 262144;
  bf16_t* v1t = wts + 524288;
  bf16_t* o1t = wts + 786432;
  bf16_t* q2t = wts + 1048576;
  bf16_t* k2t = wts + 1310720;
  bf16_t* v2t = wts + 1703936;
  bf16_t* o2t = wts + 2097152;
  bf16_t* ffint = wts + 2359296;
  bf16_t* ffoutt = wts + 4456448;

  // weight transposes fp32[K][N] -> bf16[N][K]
  wtrans_kernel<<<dim3(16, 16), 256, 0, stream>>>(q1_w, q1t, 512, 512);
  wtrans_kernel<<<dim3(16, 16), 256, 0, stream>>>(k1_w, k1t, 512, 512);
  wtrans_kernel<<<dim3(16, 16), 256, 0, stream>>>(v1_w, v1t, 512, 512);
  wtrans_kernel<<<dim3(16, 16), 256, 0, stream>>>(o1_w, o1t, 512, 512);
  wtrans_kernel<<<dim3(16, 16), 256, 0, stream>>>(q2_w, q2t, 512, 512);
  wtrans_kernel<<<dim3(24, 16), 256, 0, stream>>>(k2_w, k2t, 768, 512);
  wtrans_kernel<<<dim3(24, 16), 256, 0, stream>>>(v2_w, v2t, 768, 512);
  wtrans_kernel<<<dim3(16, 16), 256, 0, stream>>>(o2_w, o2t, 512, 512);
  wtrans_kernel<<<dim3(16, 128), 256, 0, stream>>>(ff_in_w, ffint, 512, 4096);
  wtrans_kernel<<<dim3(64, 16), 256, 0, stream>>>(ff_out_w, ffoutt, 2048, 512);
  cvt_kernel<<<384, 256, 0, stream>>>(ctx, ctxb);  // 2*256*768

  // ---- self-attention ----
  ln_kernel<<<2048, 256, 0, stream>>>(x, ln1_g, ln1_b, hb);
  // fused Q|K projection: C[8192][1024] (cols 0..511 Q, 512..1023 K)
  gemm_kernel<128, 128, 0><<<dim3(64, 8), 256, 0, stream>>>(
      hb, q1t, nullptr, nullptr, qkb, 8192, 1024, 512, 0, 1024);
  // V^T = v1t @ hb^T -> vtg[vdim][token], ldo = 8192
  gemm_kernel<64, 128, 0><<<dim3(8, 64), 256, 0, stream>>>(
      v1t, hb, nullptr, nullptr, vtg, 512, 8192, 512, 0, 8192);
  attn_kernel<<<dim3(64, 8, 2), 256, 0, stream>>>(qkb, 1024, qkb + 512, 1024,
                                                  vtg, ao, 4096);
  gemm_kernel<64, 128, 1><<<dim3(128, 4), 256, 0, stream>>>(
      ao, o1t, o1_b, x, xr, 8192, 512, 512, 0, 512);

  // ---- cross-attention ----
  ln_kernel<<<2048, 256, 0, stream>>>(xr, ln2_g, ln2_b, hb);
  gemm_kernel<64, 128, 0><<<dim3(128, 4), 256, 0, stream>>>(
      hb, q2t, nullptr, nullptr, qkb, 8192, 512, 512, 0, 512);
  gemm_kernel<64, 128, 0><<<dim3(8, 4), 256, 0, stream>>>(
      ctxb, k2t, nullptr, nullptr, kb, 512, 512, 768, 0, 512);
  gemm_kernel<64, 128, 0><<<dim3(8, 4), 256, 0, stream>>>(
      v2t, ctxb, nullptr, nullptr, vtg2, 512, 512, 768, 0, 512);
  attn_kernel<<<dim3(64, 8, 2), 256, 0, stream>>>(qkb, 512, kb, 512, vtg2, ao,
                                                  256);
  gemm_kernel<64, 128, 1><<<dim3(128, 4), 256, 0, stream>>>(
      ao, o2t, o2_b, xr, xr, 8192, 512, 512, 0, 512);

  // ---- GEGLU FF ----
  ln_kernel<<<2048, 256, 0, stream>>>(xr, ln3_g, ln3_b, hb);
  gemm_kernel<128, 64, 2><<<dim3(64, 32), 256, 0, stream>>>(
      hb, ffint, ff_in_b, nullptr, ffmid, 8192, 2048, 512, 2048, 2048);
  gemm_kernel<64, 128, 1><<<dim3(128, 4), 256, 0, stream>>>(
      ffmid, ffoutt, ff_out_b, xr, (float*)d_out, 8192, 512, 2048, 0, 512);
}

// Round 6
// 355.588 us; speedup vs baseline: 1.6647x; 1.0266x over previous
//
#include <hip/hip_runtime.h>
#include <hip/hip_bf16.h>
#include <cstdint>

// ---------------------------------------------------------------------------
// BasicTransformerBlock: LN -> self-attn -> LN -> cross-attn -> LN -> GEGLU FF
// B=2, N=4096, DIM=512, HEADS=8, D_HEAD=64, CTX: M=256, CD=768, FF_INNER=2048
// fp32 residual/LN, bf16 MFMA GEMMs + flash attention.
// R6: attn -- 32 q-rows per wave (2 q-groups share K/V fragment reads),
//     128 q-rows per block; softmax scale folded into Q weights at wtrans.
// ---------------------------------------------------------------------------

typedef __bf16 bf16_t;
typedef __bf16 bf16x8 __attribute__((ext_vector_type(8)));
typedef __bf16 bf16x4 __attribute__((ext_vector_type(4)));
typedef float f32x4 __attribute__((ext_vector_type(4)));
typedef unsigned int u32x4 __attribute__((ext_vector_type(4)));

__device__ __forceinline__ bf16_t f2bf(float f) { return (bf16_t)f; }

__device__ __forceinline__ f32x4 mfma16(bf16x8 a, bf16x8 b, f32x4 c) {
  return __builtin_amdgcn_mfma_f32_16x16x32_bf16(a, b, c, 0, 0, 0);
}

__device__ __forceinline__ float gelu_exact(float x) {
  return 0.5f * x * (1.0f + erff(x * 0.70710678118654752f));
}

// async global->LDS, 16B per lane; lds base must be wave-uniform (HW writes
// base + lane*16), global address is per-lane.
__device__ __forceinline__ void gload_lds16(const bf16_t* g, bf16_t* lds) {
  __builtin_amdgcn_global_load_lds(
      (const __attribute__((address_space(1))) unsigned int*)g,
      (__attribute__((address_space(3))) unsigned int*)lds, 16, 0, 0);
}

// ---------------------------------------------------------------------------
// LayerNorm: one wave per row of 512 fp32; writes bf16.
// ---------------------------------------------------------------------------
__global__ __launch_bounds__(256) void ln_kernel(const float* __restrict__ in,
                                                 const float* __restrict__ gw,
                                                 const float* __restrict__ bw,
                                                 bf16_t* __restrict__ out) {
  int w = threadIdx.x >> 6, l = threadIdx.x & 63;
  size_t row = (size_t)blockIdx.x * 4 + w;
  const float* p = in + row * 512 + l * 8;
  f32x4 va = *(const f32x4*)p;
  f32x4 vb = *(const f32x4*)(p + 4);
  float xs[8] = {va[0], va[1], va[2], va[3], vb[0], vb[1], vb[2], vb[3]};
  float s = 0.f;
#pragma unroll
  for (int j = 0; j < 8; j++) s += xs[j];
#pragma unroll
  for (int m = 1; m < 64; m <<= 1) s += __shfl_xor(s, m);
  float mu = s * (1.0f / 512.0f);
  float v = 0.f;
#pragma unroll
  for (int j = 0; j < 8; j++) { float d = xs[j] - mu; v += d * d; }
#pragma unroll
  for (int m = 1; m < 64; m <<= 1) v += __shfl_xor(v, m);
  float rstd = rsqrtf(v * (1.0f / 512.0f) + 1e-5f);
  f32x4 g0 = *(const f32x4*)(gw + l * 8);
  f32x4 g1 = *(const f32x4*)(gw + l * 8 + 4);
  f32x4 b0 = *(const f32x4*)(bw + l * 8);
  f32x4 b1 = *(const f32x4*)(bw + l * 8 + 4);
  bf16x8 o;
#pragma unroll
  for (int j = 0; j < 4; j++) o[j] = f2bf((xs[j] - mu) * rstd * g0[j] + b0[j]);
#pragma unroll
  for (int j = 0; j < 4; j++) o[4 + j] = f2bf((xs[4 + j] - mu) * rstd * g1[j] + b1[j]);
  *(bf16x8*)(out + row * 512 + l * 8) = o;
}

// ---------------------------------------------------------------------------
// Weight transpose+convert: W fp32 [K][N] -> Wt bf16 [N][K], scaled by sc.
// ---------------------------------------------------------------------------
__global__ __launch_bounds__(256) void wtrans_kernel(const float* __restrict__ W,
                                                     bf16_t* __restrict__ Wt,
                                                     int K, int N, float sc) {
  __shared__ float t[32][33];
  int k0 = blockIdx.x * 32, n0 = blockIdx.y * 32;
#pragma unroll
  for (int i = 0; i < 4; i++) {
    int idx = threadIdx.x + i * 256;
    int kk = idx >> 5, nn = idx & 31;
    t[kk][nn] = W[(size_t)(k0 + kk) * N + n0 + nn];
  }
  __syncthreads();
#pragma unroll
  for (int i = 0; i < 4; i++) {
    int idx = threadIdx.x + i * 256;
    int nn = idx >> 5, kk = idx & 31;
    Wt[(size_t)(n0 + nn) * K + k0 + kk] = f2bf(t[kk][nn] * sc);
  }
}

// fp32 -> bf16 elementwise (n multiple of 1024)
__global__ __launch_bounds__(256) void cvt_kernel(const float* __restrict__ in,
                                                  bf16_t* __restrict__ out) {
  int i = (blockIdx.x * 256 + threadIdx.x) * 4;
  f32x4 v = *(const f32x4*)(in + i);
  out[i + 0] = f2bf(v[0]);
  out[i + 1] = f2bf(v[1]);
  out[i + 2] = f2bf(v[2]);
  out[i + 3] = f2bf(v[3]);
}

// ---------------------------------------------------------------------------
// GEMM: C[M][N] = A[M][K](bf16) @ B (given as Bt bf16 [N][K]).
// Template: BM in {64,128}, BN in {64,128}. 256 threads, 2x2 wave grid,
// global_load_lds width=16 staging, linear double-buffered LDS, 2-phase.
// EPI 0: write bf16 out.
// EPI 1: write fp32 out = acc + bias[col] + res[row*ldo+col].
// EPI 2 (BN=64): GEGLU: val=acc+bias[col], gate=acc2+bias[col+gateOff],
//                out bf16 = val * gelu(gate). B rows 0..63 val, 64..127 gate.
// ---------------------------------------------------------------------------
template <int BM, int BN, int EPI>
__global__ __launch_bounds__(256) void gemm_kernel(
    const bf16_t* __restrict__ A, const bf16_t* __restrict__ Bt,
    const float* __restrict__ bias, const float* __restrict__ res,
    void* __restrict__ outp, int M, int N, int K, int gateOff, int ldo) {
  constexpr int WR = BM / 2;
  constexpr int WN = BN / 2;
  constexpr int MF = WR / 16;
  constexpr int NF = WN / 16;
  constexpr int ABLK = BM / 64;
  constexpr int BROWS = (EPI == 2) ? 2 * BN : BN;
  constexpr int BBLK = BROWS / 64;
  __shared__ bf16_t Al[2][BM][32];
  __shared__ bf16_t Bl[2][BROWS][32];

  int tid = threadIdx.x;
  int w = tid >> 6, l = tid & 63;
  int wr = w >> 1, wc = w & 1;
  int lg = l >> 4, lc = l & 15;
  int m0 = blockIdx.x * BM, n0 = blockIdx.y * BN;

  f32x4 acc[MF][NF] = {};
  f32x4 acc2[MF][NF] = {};

  // staging: each lane covers 16B at (srow, scol) within a 64-row block.
  int srow = tid >> 2, scol = (tid & 3) * 8;
  const bf16_t* aP[ABLK];
#pragma unroll
  for (int i = 0; i < ABLK; i++)
    aP[i] = A + (size_t)(m0 + i * 64 + srow) * K + scol;
  const bf16_t* bP[BBLK];
  if (EPI == 2) {
    bP[0] = Bt + (size_t)(n0 + srow) * K + scol;
    bP[1] = Bt + (size_t)(n0 + gateOff + srow) * K + scol;
  } else {
#pragma unroll
    for (int i = 0; i < BBLK; i++)
      bP[i] = Bt + (size_t)(n0 + i * 64 + srow) * K + scol;
  }

  auto STAGE = [&](int buf, int k0) {
#pragma unroll
    for (int i = 0; i < ABLK; i++)
      gload_lds16(aP[i] + k0, &Al[buf][i * 64 + w * 16][0]);
#pragma unroll
    for (int i = 0; i < BBLK; i++)
      gload_lds16(bP[i] + k0, &Bl[buf][i * 64 + w * 16][0]);
  };

  int nk = K / 32;
  int cur = 0;
  STAGE(0, 0);
  __syncthreads();  // vmcnt(0) drain + barrier: buf0 ready

  for (int t = 0; t < nk; ++t) {
    if (t + 1 < nk) STAGE(cur ^ 1, (t + 1) * 32);  // in flight during compute

    bf16x8 af[MF];
#pragma unroll
    for (int mi = 0; mi < MF; mi++)
      af[mi] = *(const bf16x8*)&Al[cur][wr * WR + mi * 16 + lc][lg * 8];
    bf16x8 bfr[NF];
#pragma unroll
    for (int ni = 0; ni < NF; ni++)
      bfr[ni] = *(const bf16x8*)&Bl[cur][wc * WN + ni * 16 + lc][lg * 8];
#pragma unroll
    for (int mi = 0; mi < MF; mi++)
#pragma unroll
      for (int ni = 0; ni < NF; ni++)
        acc[mi][ni] = mfma16(af[mi], bfr[ni], acc[mi][ni]);
    if (EPI == 2) {
      bf16x8 bg[NF];
#pragma unroll
      for (int ni = 0; ni < NF; ni++)
        bg[ni] = *(const bf16x8*)&Bl[cur][BN + wc * WN + ni * 16 + lc][lg * 8];
#pragma unroll
      for (int mi = 0; mi < MF; mi++)
#pragma unroll
        for (int ni = 0; ni < NF; ni++)
          acc2[mi][ni] = mfma16(af[mi], bg[ni], acc2[mi][ni]);
    }
    __syncthreads();  // next tile landed + read-write hazard
    cur ^= 1;
  }

#pragma unroll
  for (int mi = 0; mi < MF; mi++) {
#pragma unroll
    for (int ni = 0; ni < NF; ni++) {
#pragma unroll
      for (int r = 0; r < 4; r++) {
        int row = m0 + wr * WR + mi * 16 + lg * 4 + r;
        int col = n0 + wc * WN + ni * 16 + lc;
        float v = acc[mi][ni][r];
        if (EPI == 0) {
          ((bf16_t*)outp)[(size_t)row * ldo + col] = f2bf(v);
        } else if (EPI == 1) {
          ((float*)outp)[(size_t)row * ldo + col] =
              v + bias[col] + res[(size_t)row * ldo + col];
        } else {
          float g = acc2[mi][ni][r] + bias[col + gateOff];
          float val = v + bias[col];
          ((bf16_t*)outp)[(size_t)row * ldo + col] = f2bf(val * gelu_exact(g));
        }
      }
    }
  }
}

// ---------------------------------------------------------------------------
// Flash attention. Block = 256 threads (4 waves); one (b, head, 128 q-rows)
// per block; each wave owns 32 q-rows (2 q-groups of 16). KV tiles 64.
// Swapped QK^T: C[key][q]; each K/V fragment read feeds both q-groups.
// Lane-local softmax (q = qg*16+lc per lane), defer-max, b64 P-repack,
// row-sums via ones-MFMA. Softmax scale pre-folded into Q projection.
// Q rows stride ldq, K rows stride ldk. V pre-transposed: Vt[vdim][token].
// ---------------------------------------------------------------------------
__global__ __launch_bounds__(256) void attn_kernel(
    const bf16_t* __restrict__ Q, int ldq, const bf16_t* __restrict__ Kb,
    int ldk, const bf16_t* __restrict__ Vt, bf16_t* __restrict__ O, int Mkv) {
  __shared__ bf16_t Klds[64][72];
  __shared__ bf16_t Vlds[64][72];
  __shared__ bf16_t Plds[4][32][72];

  int qt = blockIdx.x, head = blockIdx.y, b = blockIdx.z;
  int tid = threadIdx.x;
  int w = tid >> 6, l = tid & 63;
  int lg = l >> 4, lc = l & 15;
  int ldv = 2 * Mkv;

  // q rows: qrow0 + qg*16 + lc  (lane holds softmax state for that q)
  size_t qrow0 = (size_t)b * 4096 + qt * 128 + w * 32;
  bf16x8 bq[2][2];
#pragma unroll
  for (int qg = 0; qg < 2; qg++) {
    const bf16_t* qp = Q + (qrow0 + qg * 16 + lc) * ldq + head * 64;
    bq[qg][0] = *(const bf16x8*)(qp + lg * 8);
    bq[qg][1] = *(const bf16x8*)(qp + 32 + lg * 8);
  }

  f32x4 o[2][4] = {};
  f32x4 zacc[2] = {};
  float mrun[2] = {-1e30f, -1e30f};

  bf16x8 vones;
#pragma unroll
  for (int j = 0; j < 8; j++) vones[j] = f2bf(1.0f);

  int key0 = tid >> 2, dc0 = (tid & 3) * 16;
  const bf16_t* kp = Kb + ((size_t)b * Mkv + key0) * ldk + head * 64 + dc0;
  const bf16_t* vp = Vt + (size_t)(head * 64 + key0) * ldv + b * Mkv + dc0;

  // prefetch tile 0
  bf16x8 kc0 = *(const bf16x8*)kp, kc1 = *(const bf16x8*)(kp + 8);
  bf16x8 vc0 = *(const bf16x8*)vp, vc1 = *(const bf16x8*)(vp + 8);

  for (int t0 = 0; t0 < Mkv; t0 += 64) {
    __syncthreads();  // previous tile's LDS reads complete
    *(bf16x8*)&Klds[key0][dc0] = kc0;
    *(bf16x8*)&Klds[key0][dc0 + 8] = kc1;
    *(bf16x8*)&Vlds[key0][dc0] = vc0;
    *(bf16x8*)&Vlds[key0][dc0 + 8] = vc1;
    __syncthreads();

    if (t0 + 64 < Mkv) {  // issue next-tile loads; land during compute
      kp += (size_t)64 * ldk;
      vp += 64;
      kc0 = *(const bf16x8*)kp;
      kc1 = *(const bf16x8*)(kp + 8);
      vc0 = *(const bf16x8*)vp;
      vc1 = *(const bf16x8*)(vp + 8);
    }

    // S^T = K Q^T (C[key][q]); K-frag shared by both q-groups
    f32x4 s[2][4];
    __builtin_amdgcn_s_setprio(1);
#pragma unroll
    for (int kg = 0; kg < 4; kg++) {
      bf16x8 ak0 = *(const bf16x8*)&Klds[kg * 16 + lc][lg * 8];
      bf16x8 ak1 = *(const bf16x8*)&Klds[kg * 16 + lc][32 + lg * 8];
#pragma unroll
      for (int qg = 0; qg < 2; qg++) {
        f32x4 z = {};
        z = mfma16(ak0, bq[qg][0], z);
        z = mfma16(ak1, bq[qg][1], z);
        s[qg][kg] = z;
      }
    }
    __builtin_amdgcn_s_setprio(0);

#pragma unroll
    for (int qg = 0; qg < 2; qg++) {
      f32x4 t4 = s[qg][0];
#pragma unroll
      for (int kg = 1; kg < 4; kg++) {
        t4[0] = fmaxf(t4[0], s[qg][kg][0]);
        t4[1] = fmaxf(t4[1], s[qg][kg][1]);
        t4[2] = fmaxf(t4[2], s[qg][kg][2]);
        t4[3] = fmaxf(t4[3], s[qg][kg][3]);
      }
      float tmax = fmaxf(fmaxf(t4[0], t4[1]), fmaxf(t4[2], t4[3]));
      tmax = fmaxf(tmax, __shfl_xor(tmax, 16));
      tmax = fmaxf(tmax, __shfl_xor(tmax, 32));

      if (!__all(tmax <= mrun[qg] + 8.0f)) {
        float mnew = fmaxf(mrun[qg], tmax);
        float resc = __builtin_amdgcn_exp2f(mrun[qg] - mnew);
        mrun[qg] = mnew;
        float rr[4];
#pragma unroll
        for (int r = 0; r < 4; r++) rr[r] = __shfl(resc, lg * 4 + r);
#pragma unroll
        for (int df = 0; df < 4; df++)
#pragma unroll
          for (int r = 0; r < 4; r++) o[qg][df][r] *= rr[r];
#pragma unroll
        for (int r = 0; r < 4; r++) zacc[qg][r] *= rr[r];
      }

#pragma unroll
      for (int kg = 0; kg < 4; kg++) {
        bf16x4 pv;
#pragma unroll
        for (int r = 0; r < 4; r++)
          pv[r] = f2bf(__builtin_amdgcn_exp2f(s[qg][kg][r] - mrun[qg]));
        *(bf16x4*)&Plds[w][qg * 16 + lc][kg * 16 + lg * 4] = pv;
      }
    }

    bf16x8 pa[2][2];
#pragma unroll
    for (int qg = 0; qg < 2; qg++) {
      pa[qg][0] = *(const bf16x8*)&Plds[w][qg * 16 + lc][lg * 8];
      pa[qg][1] = *(const bf16x8*)&Plds[w][qg * 16 + lc][32 + lg * 8];
    }
    __builtin_amdgcn_s_setprio(1);
#pragma unroll
    for (int qg = 0; qg < 2; qg++) {
      zacc[qg] = mfma16(pa[qg][0], vones, zacc[qg]);
      zacc[qg] = mfma16(pa[qg][1], vones, zacc[qg]);
    }
#pragma unroll
    for (int df = 0; df < 4; df++) {
      bf16x8 vb0 = *(const bf16x8*)&Vlds[df * 16 + lc][lg * 8];
      bf16x8 vb1 = *(const bf16x8*)&Vlds[df * 16 + lc][32 + lg * 8];
#pragma unroll
      for (int qg = 0; qg < 2; qg++) {
        o[qg][df] = mfma16(pa[qg][0], vb0, o[qg][df]);
        o[qg][df] = mfma16(pa[qg][1], vb1, o[qg][df]);
      }
    }
    __builtin_amdgcn_s_setprio(0);
  }

#pragma unroll
  for (int qg = 0; qg < 2; qg++) {
    float inv[4];
#pragma unroll
    for (int r = 0; r < 4; r++) inv[r] = 1.0f / zacc[qg][r];
    size_t obase = (qrow0 + qg * 16) * 512 + head * 64;
#pragma unroll
    for (int df = 0; df < 4; df++)
#pragma unroll
      for (int r = 0; r < 4; r++)
        O[obase + (size_t)(lg * 4 + r) * 512 + df * 16 + lc] =
            f2bf(o[qg][df][r] * inv[r]);
  }
}

// ---------------------------------------------------------------------------
extern "C" void kernel_launch(void* const* d_in, const int* in_sizes, int n_in,
                              void* d_out, int out_size, void* d_ws,
                              size_t ws_size, hipStream_t stream) {
  const float* x = (const float*)d_in[0];
  const float* ctx = (const float*)d_in[1];
  const float* q1_w = (const float*)d_in[2];
  const float* k1_w = (const float*)d_in[3];
  const float* v1_w = (const float*)d_in[4];
  const float* o1_w = (const float*)d_in[5];
  const float* o1_b = (const float*)d_in[6];
  const float* q2_w = (const float*)d_in[7];
  const float* k2_w = (const float*)d_in[8];
  const float* v2_w = (const float*)d_in[9];
  const float* o2_w = (const float*)d_in[10];
  const float* o2_b = (const float*)d_in[11];
  const float* ff_in_w = (const float*)d_in[12];
  const float* ff_in_b = (const float*)d_in[13];
  const float* ff_out_w = (const float*)d_in[14];
  const float* ff_out_b = (const float*)d_in[15];
  const float* ln1_g = (const float*)d_in[16];
  const float* ln1_b = (const float*)d_in[17];
  const float* ln2_g = (const float*)d_in[18];
  const float* ln2_b = (const float*)d_in[19];
  const float* ln3_g = (const float*)d_in[20];
  const float* ln3_b = (const float*)d_in[21];

  char* ws = (char*)d_ws;
  float* xr = (float*)(ws + 0);                    // 16.78 MB fp32 residual
  bf16_t* hb = (bf16_t*)(ws + 16777216);           // 8.39 MB LN output
  bf16_t* qkb = (bf16_t*)(ws + 25165824);          // 16.78 MB [8192][1024]
  bf16_t* ao = (bf16_t*)(ws + 41943040);           // 8.39 MB
  bf16_t* ffmid = qkb;                             // alias qkb+ao (33.55 MB)
  bf16_t* kb = (bf16_t*)(ws + 50331648);           // 0.52 MB cross K
  bf16_t* vtg2 = (bf16_t*)(ws + 50855936);         // 0.52 MB cross V^T
  bf16_t* ctxb = (bf16_t*)(ws + 51380224);         // 0.79 MB
  bf16_t* wts = (bf16_t*)(ws + 58720256);          // 11.01 MB bf16 weights^T
  bf16_t* vtg = (bf16_t*)(ws + 69730304);          // 8.39 MB V^T [512][8192]

  bf16_t* q1t = wts + 0;        // q1t,k1t adjacent -> fused Q|K weight
  bf16_t* k1t = wts + 262144;
  bf16_t* v1t = wts + 524288;
  bf16_t* o1t = wts + 786432;
  bf16_t* q2t = wts + 1048576;
  bf16_t* k2t = wts + 1310720;
  bf16_t* v2t = wts + 1703936;
  bf16_t* o2t = wts + 2097152;
  bf16_t* ffint = wts + 2359296;
  bf16_t* ffoutt = wts + 4456448;

  const float QS = 0.125f * 1.44269504f;  // attn scale * log2(e), folded into Q

  // weight transposes fp32[K][N] -> bf16[N][K]
  wtrans_kernel<<<dim3(16, 16), 256, 0, stream>>>(q1_w, q1t, 512, 512, QS);
  wtrans_kernel<<<dim3(16, 16), 256, 0, stream>>>(k1_w, k1t, 512, 512, 1.0f);
  wtrans_kernel<<<dim3(16, 16), 256, 0, stream>>>(v1_w, v1t, 512, 512, 1.0f);
  wtrans_kernel<<<dim3(16, 16), 256, 0, stream>>>(o1_w, o1t, 512, 512, 1.0f);
  wtrans_kernel<<<dim3(16, 16), 256, 0, stream>>>(q2_w, q2t, 512, 512, QS);
  wtrans_kernel<<<dim3(24, 16), 256, 0, stream>>>(k2_w, k2t, 768, 512, 1.0f);
  wtrans_kernel<<<dim3(24, 16), 256, 0, stream>>>(v2_w, v2t, 768, 512, 1.0f);
  wtrans_kernel<<<dim3(16, 16), 256, 0, stream>>>(o2_w, o2t, 512, 512, 1.0f);
  wtrans_kernel<<<dim3(16, 128), 256, 0, stream>>>(ff_in_w, ffint, 512, 4096, 1.0f);
  wtrans_kernel<<<dim3(64, 16), 256, 0, stream>>>(ff_out_w, ffoutt, 2048, 512, 1.0f);
  cvt_kernel<<<384, 256, 0, stream>>>(ctx, ctxb);  // 2*256*768

  // ---- self-attention ----
  ln_kernel<<<2048, 256, 0, stream>>>(x, ln1_g, ln1_b, hb);
  // fused Q|K projection: C[8192][1024] (cols 0..511 Q, 512..1023 K)
  gemm_kernel<128, 128, 0><<<dim3(64, 8), 256, 0, stream>>>(
      hb, q1t, nullptr, nullptr, qkb, 8192, 1024, 512, 0, 1024);
  // V^T = v1t @ hb^T -> vtg[vdim][token], ldo = 8192
  gemm_kernel<64, 128, 0><<<dim3(8, 64), 256, 0, stream>>>(
      v1t, hb, nullptr, nullptr, vtg, 512, 8192, 512, 0, 8192);
  attn_kernel<<<dim3(32, 8, 2), 256, 0, stream>>>(qkb, 1024, qkb + 512, 1024,
                                                  vtg, ao, 4096);
  gemm_kernel<64, 128, 1><<<dim3(128, 4), 256, 0, stream>>>(
      ao, o1t, o1_b, x, xr, 8192, 512, 512, 0, 512);

  // ---- cross-attention ----
  ln_kernel<<<2048, 256, 0, stream>>>(xr, ln2_g, ln2_b, hb);
  gemm_kernel<64, 128, 0><<<dim3(128, 4), 256, 0, stream>>>(
      hb, q2t, nullptr, nullptr, qkb, 8192, 512, 512, 0, 512);
  gemm_kernel<64, 128, 0><<<dim3(8, 4), 256, 0, stream>>>(
      ctxb, k2t, nullptr, nullptr, kb, 512, 512, 768, 0, 512);
  gemm_kernel<64, 128, 0><<<dim3(8, 4), 256, 0, stream>>>(
      v2t, ctxb, nullptr, nullptr, vtg2, 512, 512, 768, 0, 512);
  attn_kernel<<<dim3(32, 8, 2), 256, 0, stream>>>(qkb, 512, kb, 512, vtg2, ao,
                                                  256);
  gemm_kernel<64, 128, 1><<<dim3(128, 4), 256, 0, stream>>>(
      ao, o2t, o2_b, xr, xr, 8192, 512, 512, 0, 512);

  // ---- GEGLU FF ----
  ln_kernel<<<2048, 256, 0, stream>>>(xr, ln3_g, ln3_b, hb);
  gemm_kernel<128, 64, 2><<<dim3(64, 32), 256, 0, stream>>>(
      hb, ffint, ff_in_b, nullptr, ffmid, 8192, 2048, 512, 2048, 2048);
  gemm_kernel<64, 128, 1><<<dim3(128, 4), 256, 0, stream>>>(
      ffmid, ffoutt, ff_out_b, xr, (float*)d_out, 8192, 512, 2048, 0, 512);
}

// Round 7
// 335.599 us; speedup vs baseline: 1.7638x; 1.0596x over previous
//
#include <hip/hip_runtime.h>
#include <hip/hip_bf16.h>
#include <cstdint>

// ---------------------------------------------------------------------------
// BasicTransformerBlock: LN -> self-attn -> LN -> cross-attn -> LN -> GEGLU FF
// B=2, N=4096, DIM=512, HEADS=8, D_HEAD=64, CTX: M=256, CD=768, FF_INNER=2048
// fp32 residual/LN, bf16 MFMA GEMMs + flash attention.
// R7: attn on 32x32x16 MFMA -- C[key][q] swapped QK^T, P kept entirely in
//     registers (key-order chosen so PV A-frags are lane-local; V token
//     columns bit-2/3-swapped at V^T GEMM epilogue to match). Plds deleted.
// ---------------------------------------------------------------------------

typedef __bf16 bf16_t;
typedef __bf16 bf16x8 __attribute__((ext_vector_type(8)));
typedef float f32x4 __attribute__((ext_vector_type(4)));
typedef float f32x16 __attribute__((ext_vector_type(16)));
typedef unsigned int u32x4 __attribute__((ext_vector_type(4)));

__device__ __forceinline__ bf16_t f2bf(float f) { return (bf16_t)f; }

__device__ __forceinline__ f32x4 mfma16(bf16x8 a, bf16x8 b, f32x4 c) {
  return __builtin_amdgcn_mfma_f32_16x16x32_bf16(a, b, c, 0, 0, 0);
}
__device__ __forceinline__ f32x16 mfma32(bf16x8 a, bf16x8 b, f32x16 c) {
  return __builtin_amdgcn_mfma_f32_32x32x16_bf16(a, b, c, 0, 0, 0);
}

__device__ __forceinline__ float gelu_exact(float x) {
  return 0.5f * x * (1.0f + erff(x * 0.70710678118654752f));
}

// async global->LDS, 16B per lane; lds base must be wave-uniform (HW writes
// base + lane*16), global address is per-lane.
__device__ __forceinline__ void gload_lds16(const bf16_t* g, bf16_t* lds) {
  __builtin_amdgcn_global_load_lds(
      (const __attribute__((address_space(1))) unsigned int*)g,
      (__attribute__((address_space(3))) unsigned int*)lds, 16, 0, 0);
}

// ---------------------------------------------------------------------------
// LayerNorm: one wave per row of 512 fp32; writes bf16.
// ---------------------------------------------------------------------------
__global__ __launch_bounds__(256) void ln_kernel(const float* __restrict__ in,
                                                 const float* __restrict__ gw,
                                                 const float* __restrict__ bw,
                                                 bf16_t* __restrict__ out) {
  int w = threadIdx.x >> 6, l = threadIdx.x & 63;
  size_t row = (size_t)blockIdx.x * 4 + w;
  const float* p = in + row * 512 + l * 8;
  f32x4 va = *(const f32x4*)p;
  f32x4 vb = *(const f32x4*)(p + 4);
  float xs[8] = {va[0], va[1], va[2], va[3], vb[0], vb[1], vb[2], vb[3]};
  float s = 0.f;
#pragma unroll
  for (int j = 0; j < 8; j++) s += xs[j];
#pragma unroll
  for (int m = 1; m < 64; m <<= 1) s += __shfl_xor(s, m);
  float mu = s * (1.0f / 512.0f);
  float v = 0.f;
#pragma unroll
  for (int j = 0; j < 8; j++) { float d = xs[j] - mu; v += d * d; }
#pragma unroll
  for (int m = 1; m < 64; m <<= 1) v += __shfl_xor(v, m);
  float rstd = rsqrtf(v * (1.0f / 512.0f) + 1e-5f);
  f32x4 g0 = *(const f32x4*)(gw + l * 8);
  f32x4 g1 = *(const f32x4*)(gw + l * 8 + 4);
  f32x4 b0 = *(const f32x4*)(bw + l * 8);
  f32x4 b1 = *(const f32x4*)(bw + l * 8 + 4);
  bf16x8 o;
#pragma unroll
  for (int j = 0; j < 4; j++) o[j] = f2bf((xs[j] - mu) * rstd * g0[j] + b0[j]);
#pragma unroll
  for (int j = 0; j < 4; j++) o[4 + j] = f2bf((xs[4 + j] - mu) * rstd * g1[j] + b1[j]);
  *(bf16x8*)(out + row * 512 + l * 8) = o;
}

// ---------------------------------------------------------------------------
// Weight transpose+convert: W fp32 [K][N] -> Wt bf16 [N][K], scaled by sc.
// ---------------------------------------------------------------------------
__global__ __launch_bounds__(256) void wtrans_kernel(const float* __restrict__ W,
                                                     bf16_t* __restrict__ Wt,
                                                     int K, int N, float sc) {
  __shared__ float t[32][33];
  int k0 = blockIdx.x * 32, n0 = blockIdx.y * 32;
#pragma unroll
  for (int i = 0; i < 4; i++) {
    int idx = threadIdx.x + i * 256;
    int kk = idx >> 5, nn = idx & 31;
    t[kk][nn] = W[(size_t)(k0 + kk) * N + n0 + nn];
  }
  __syncthreads();
#pragma unroll
  for (int i = 0; i < 4; i++) {
    int idx = threadIdx.x + i * 256;
    int nn = idx >> 5, kk = idx & 31;
    Wt[(size_t)(n0 + nn) * K + k0 + kk] = f2bf(t[kk][nn] * sc);
  }
}

// fp32 -> bf16 elementwise (n multiple of 1024)
__global__ __launch_bounds__(256) void cvt_kernel(const float* __restrict__ in,
                                                  bf16_t* __restrict__ out) {
  int i = (blockIdx.x * 256 + threadIdx.x) * 4;
  f32x4 v = *(const f32x4*)(in + i);
  out[i + 0] = f2bf(v[0]);
  out[i + 1] = f2bf(v[1]);
  out[i + 2] = f2bf(v[2]);
  out[i + 3] = f2bf(v[3]);
}

// ---------------------------------------------------------------------------
// GEMM: C[M][N] = A[M][K](bf16) @ B (given as Bt bf16 [N][K]).
// Template: BM in {64,128}, BN in {64,128}. 256 threads, 2x2 wave grid,
// global_load_lds width=16 staging, linear double-buffered LDS, 2-phase.
// EPI 0: write bf16 out.
// EPI 1: write fp32 out = acc + bias[col] + res[row*ldo+col].
// EPI 2 (BN=64): GEGLU dual-acc, out bf16 = val * gelu(gate).
// EPI 3: bf16 out with column bits 2<->3 swapped (V^T token permutation).
// ---------------------------------------------------------------------------
template <int BM, int BN, int EPI>
__global__ __launch_bounds__(256) void gemm_kernel(
    const bf16_t* __restrict__ A, const bf16_t* __restrict__ Bt,
    const float* __restrict__ bias, const float* __restrict__ res,
    void* __restrict__ outp, int M, int N, int K, int gateOff, int ldo) {
  constexpr int WR = BM / 2;
  constexpr int WN = BN / 2;
  constexpr int MF = WR / 16;
  constexpr int NF = WN / 16;
  constexpr int ABLK = BM / 64;
  constexpr int BROWS = (EPI == 2) ? 2 * BN : BN;
  constexpr int BBLK = BROWS / 64;
  __shared__ bf16_t Al[2][BM][32];
  __shared__ bf16_t Bl[2][BROWS][32];

  int tid = threadIdx.x;
  int w = tid >> 6, l = tid & 63;
  int wr = w >> 1, wc = w & 1;
  int lg = l >> 4, lc = l & 15;
  int m0 = blockIdx.x * BM, n0 = blockIdx.y * BN;

  f32x4 acc[MF][NF] = {};
  f32x4 acc2[MF][NF] = {};

  int srow = tid >> 2, scol = (tid & 3) * 8;
  const bf16_t* aP[ABLK];
#pragma unroll
  for (int i = 0; i < ABLK; i++)
    aP[i] = A + (size_t)(m0 + i * 64 + srow) * K + scol;
  const bf16_t* bP[BBLK];
  if (EPI == 2) {
    bP[0] = Bt + (size_t)(n0 + srow) * K + scol;
    bP[1] = Bt + (size_t)(n0 + gateOff + srow) * K + scol;
  } else {
#pragma unroll
    for (int i = 0; i < BBLK; i++)
      bP[i] = Bt + (size_t)(n0 + i * 64 + srow) * K + scol;
  }

  auto STAGE = [&](int buf, int k0) {
#pragma unroll
    for (int i = 0; i < ABLK; i++)
      gload_lds16(aP[i] + k0, &Al[buf][i * 64 + w * 16][0]);
#pragma unroll
    for (int i = 0; i < BBLK; i++)
      gload_lds16(bP[i] + k0, &Bl[buf][i * 64 + w * 16][0]);
  };

  int nk = K / 32;
  int cur = 0;
  STAGE(0, 0);
  __syncthreads();

  for (int t = 0; t < nk; ++t) {
    if (t + 1 < nk) STAGE(cur ^ 1, (t + 1) * 32);

    bf16x8 af[MF];
#pragma unroll
    for (int mi = 0; mi < MF; mi++)
      af[mi] = *(const bf16x8*)&Al[cur][wr * WR + mi * 16 + lc][lg * 8];
    bf16x8 bfr[NF];
#pragma unroll
    for (int ni = 0; ni < NF; ni++)
      bfr[ni] = *(const bf16x8*)&Bl[cur][wc * WN + ni * 16 + lc][lg * 8];
#pragma unroll
    for (int mi = 0; mi < MF; mi++)
#pragma unroll
      for (int ni = 0; ni < NF; ni++)
        acc[mi][ni] = mfma16(af[mi], bfr[ni], acc[mi][ni]);
    if (EPI == 2) {
      bf16x8 bg[NF];
#pragma unroll
      for (int ni = 0; ni < NF; ni++)
        bg[ni] = *(const bf16x8*)&Bl[cur][BN + wc * WN + ni * 16 + lc][lg * 8];
#pragma unroll
      for (int mi = 0; mi < MF; mi++)
#pragma unroll
        for (int ni = 0; ni < NF; ni++)
          acc2[mi][ni] = mfma16(af[mi], bg[ni], acc2[mi][ni]);
    }
    __syncthreads();
    cur ^= 1;
  }

#pragma unroll
  for (int mi = 0; mi < MF; mi++) {
#pragma unroll
    for (int ni = 0; ni < NF; ni++) {
#pragma unroll
      for (int r = 0; r < 4; r++) {
        int row = m0 + wr * WR + mi * 16 + lg * 4 + r;
        int col = n0 + wc * WN + ni * 16 + lc;
        float v = acc[mi][ni][r];
        if (EPI == 0) {
          ((bf16_t*)outp)[(size_t)row * ldo + col] = f2bf(v);
        } else if (EPI == 3) {
          int cs = (col & ~15) | (lc & 3) | ((lc & 4) << 1) | ((lc & 8) >> 1);
          ((bf16_t*)outp)[(size_t)row * ldo + cs] = f2bf(v);
        } else if (EPI == 1) {
          ((float*)outp)[(size_t)row * ldo + col] =
              v + bias[col] + res[(size_t)row * ldo + col];
        } else {
          float g = acc2[mi][ni][r] + bias[col + gateOff];
          float val = v + bias[col];
          ((bf16_t*)outp)[(size_t)row * ldo + col] = f2bf(val * gelu_exact(g));
        }
      }
    }
  }
}

// ---------------------------------------------------------------------------
// Flash attention on 32x32x16 MFMA. Block = 256 threads (4 waves); each wave
// owns 32 q-rows (q = lane&31); block covers 128 q-rows of one (b, head).
// KV tiles of 64. QK^T = mfma32(K, Q) -> C[key][q]; lane (q,hi) holds S for
// keys {(r&3)+8*(r>>2)+4*hi} per 32-key tile -> softmax is lane-local with
// one shfl_xor(32). PV A-frags are the lane's OWN P registers because the
// MFMA k-order is chosen as kappa = 16m + (j&3)+8*(j>>2)+4*hi; V is stored
// with token bits 2<->3 pre-swapped (EPI=3 GEMM) so B-frags read contiguous.
// Row-sums via ones-MFMA (matrix pipe). Softmax scale pre-folded into Q.
// V pre-transposed+permuted in global: Vt[vdim][token], ldv = 2*Mkv.
// ---------------------------------------------------------------------------
__global__ __launch_bounds__(256) void attn_kernel(
    const bf16_t* __restrict__ Q, int ldq, const bf16_t* __restrict__ Kb,
    int ldk, const bf16_t* __restrict__ Vt, bf16_t* __restrict__ O, int Mkv) {
  __shared__ bf16_t Klds[64][72];  // rows = key, cols = d
  __shared__ bf16_t Vlds[64][72];  // rows = d, cols = permuted token

  int qt = blockIdx.x, head = blockIdx.y, b = blockIdx.z;
  int tid = threadIdx.x;
  int w = tid >> 6, l = tid & 63;
  int ql = l & 31, hi = l >> 5;
  int ldv = 2 * Mkv;

  // Q B-frags: qf[dk] covers d = dk*16 + hi*8 + j for q = ql
  size_t qrow = (size_t)b * 4096 + qt * 128 + w * 32 + ql;
  const bf16_t* qp = Q + qrow * ldq + head * 64 + hi * 8;
  bf16x8 qf[4];
#pragma unroll
  for (int dk = 0; dk < 4; dk++) qf[dk] = *(const bf16x8*)(qp + dk * 16);

  f32x16 o0 = {}, o1 = {};  // O[q][d]: d = ql (o0) / 32+ql (o1), q from reg
  f32x16 zacc = {};
  float mrun = -1e30f;

  bf16x8 vones;
#pragma unroll
  for (int j = 0; j < 8; j++) vones[j] = f2bf(1.0f);

  int key0 = tid >> 2, dc0 = (tid & 3) * 16;
  const bf16_t* kp = Kb + ((size_t)b * Mkv + key0) * ldk + head * 64 + dc0;
  const bf16_t* vp = Vt + (size_t)(head * 64 + key0) * ldv + b * Mkv + dc0;

  // prefetch tile 0
  bf16x8 kc0 = *(const bf16x8*)kp, kc1 = *(const bf16x8*)(kp + 8);
  bf16x8 vc0 = *(const bf16x8*)vp, vc1 = *(const bf16x8*)(vp + 8);

  for (int t0 = 0; t0 < Mkv; t0 += 64) {
    __syncthreads();  // previous tile's LDS reads complete
    *(bf16x8*)&Klds[key0][dc0] = kc0;
    *(bf16x8*)&Klds[key0][dc0 + 8] = kc1;
    *(bf16x8*)&Vlds[key0][dc0] = vc0;
    *(bf16x8*)&Vlds[key0][dc0 + 8] = vc1;
    __syncthreads();

    if (t0 + 64 < Mkv) {  // issue next-tile loads; land during compute
      kp += (size_t)64 * ldk;
      vp += 64;
      kc0 = *(const bf16x8*)kp;
      kc1 = *(const bf16x8*)(kp + 8);
      vc0 = *(const bf16x8*)vp;
      vc1 = *(const bf16x8*)(vp + 8);
    }

    // S^T = K Q^T: s0 = keys 0..31, s1 = keys 32..63 (C[key][q])
    f32x16 s0 = {}, s1 = {};
    __builtin_amdgcn_s_setprio(1);
#pragma unroll
    for (int dk = 0; dk < 4; dk++) {
      bf16x8 a0 = *(const bf16x8*)&Klds[ql][dk * 16 + hi * 8];
      bf16x8 a1 = *(const bf16x8*)&Klds[32 + ql][dk * 16 + hi * 8];
      s0 = mfma32(a0, qf[dk], s0);
      s1 = mfma32(a1, qf[dk], s1);
    }
    __builtin_amdgcn_s_setprio(0);

    // lane-local max over own 32 values + 1 cross-half shfl
    float tmax = s0[0];
#pragma unroll
    for (int r = 1; r < 16; r++) tmax = fmaxf(tmax, s0[r]);
#pragma unroll
    for (int r = 0; r < 16; r++) tmax = fmaxf(tmax, s1[r]);
    tmax = fmaxf(tmax, __shfl_xor(tmax, 32));

    // defer-max rescale (log2 domain, threshold 8)
    if (!__all(tmax <= mrun + 8.0f)) {
      float mnew = fmaxf(mrun, tmax);
      float resc = __builtin_amdgcn_exp2f(mrun - mnew);
      mrun = mnew;
#pragma unroll
      for (int r = 0; r < 16; r++) {
        float f = __shfl(resc, (r & 3) + 8 * (r >> 2) + 4 * hi);
        o0[r] *= f;
        o1[r] *= f;
        zacc[r] *= f;
      }
    }

    // P fragments: chunk m uses own regs s[kt= m>>1][8*(m&1) + j]
    bf16x8 pa[4];
#pragma unroll
    for (int m = 0; m < 4; m++) {
#pragma unroll
      for (int j = 0; j < 8; j++) {
        float sv = (m < 2) ? s0[(m & 1) * 8 + j] : s1[(m & 1) * 8 + j];
        pa[m][j] = f2bf(__builtin_amdgcn_exp2f(sv - mrun));
      }
    }

    __builtin_amdgcn_s_setprio(1);
#pragma unroll
    for (int m = 0; m < 4; m++) {
      zacc = mfma32(pa[m], vones, zacc);  // row-sums on matrix pipe
      bf16x8 vb0 = *(const bf16x8*)&Vlds[ql][m * 16 + hi * 8];
      bf16x8 vb1 = *(const bf16x8*)&Vlds[32 + ql][m * 16 + hi * 8];
      o0 = mfma32(pa[m], vb0, o0);
      o1 = mfma32(pa[m], vb1, o1);
    }
    __builtin_amdgcn_s_setprio(0);
  }

  size_t ob = ((size_t)b * 4096 + qt * 128 + w * 32) * 512 + head * 64;
#pragma unroll
  for (int r = 0; r < 16; r++) {
    float inv = 1.0f / zacc[r];
    int q = (r & 3) + 8 * (r >> 2) + 4 * hi;
    O[ob + (size_t)q * 512 + ql] = f2bf(o0[r] * inv);
    O[ob + (size_t)q * 512 + 32 + ql] = f2bf(o1[r] * inv);
  }
}

// ---------------------------------------------------------------------------
extern "C" void kernel_launch(void* const* d_in, const int* in_sizes, int n_in,
                              void* d_out, int out_size, void* d_ws,
                              size_t ws_size, hipStream_t stream) {
  const float* x = (const float*)d_in[0];
  const float* ctx = (const float*)d_in[1];
  const float* q1_w = (const float*)d_in[2];
  const float* k1_w = (const float*)d_in[3];
  const float* v1_w = (const float*)d_in[4];
  const float* o1_w = (const float*)d_in[5];
  const float* o1_b = (const float*)d_in[6];
  const float* q2_w = (const float*)d_in[7];
  const float* k2_w = (const float*)d_in[8];
  const float* v2_w = (const float*)d_in[9];
  const float* o2_w = (const float*)d_in[10];
  const float* o2_b = (const float*)d_in[11];
  const float* ff_in_w = (const float*)d_in[12];
  const float* ff_in_b = (const float*)d_in[13];
  const float* ff_out_w = (const float*)d_in[14];
  const float* ff_out_b = (const float*)d_in[15];
  const float* ln1_g = (const float*)d_in[16];
  const float* ln1_b = (const float*)d_in[17];
  const float* ln2_g = (const float*)d_in[18];
  const float* ln2_b = (const float*)d_in[19];
  const float* ln3_g = (const float*)d_in[20];
  const float* ln3_b = (const float*)d_in[21];

  char* ws = (char*)d_ws;
  float* xr = (float*)(ws + 0);                    // 16.78 MB fp32 residual
  bf16_t* hb = (bf16_t*)(ws + 16777216);           // 8.39 MB LN output
  bf16_t* qkb = (bf16_t*)(ws + 25165824);          // 16.78 MB [8192][1024]
  bf16_t* ao = (bf16_t*)(ws + 41943040);           // 8.39 MB
  bf16_t* ffmid = qkb;                             // alias qkb+ao (33.55 MB)
  bf16_t* kb = (bf16_t*)(ws + 50331648);           // 0.52 MB cross K
  bf16_t* vtg2 = (bf16_t*)(ws + 50855936);         // 0.52 MB cross V^T
  bf16_t* ctxb = (bf16_t*)(ws + 51380224);         // 0.79 MB
  bf16_t* wts = (bf16_t*)(ws + 58720256);          // 11.01 MB bf16 weights^T
  bf16_t* vtg = (bf16_t*)(ws + 69730304);          // 8.39 MB V^T [512][8192]

  bf16_t* q1t = wts + 0;        // q1t,k1t adjacent -> fused Q|K weight
  bf16_t* k1t = wts + 262144;
  bf16_t* v1t = wts + 524288;
  bf16_t* o1t = wts + 786432;
  bf16_t* q2t = wts + 1048576;
  bf16_t* k2t = wts + 1310720;
  bf16_t* v2t = wts + 1703936;
  bf16_t* o2t = wts + 2097152;
  bf16_t* ffint = wts + 2359296;
  bf16_t* ffoutt = wts + 4456448;

  const float QS = 0.125f * 1.44269504f;  // attn scale * log2(e), folded into Q

  // weight transposes fp32[K][N] -> bf16[N][K]
  wtrans_kernel<<<dim3(16, 16), 256, 0, stream>>>(q1_w, q1t, 512, 512, QS);
  wtrans_kernel<<<dim3(16, 16), 256, 0, stream>>>(k1_w, k1t, 512, 512, 1.0f);
  wtrans_kernel<<<dim3(16, 16), 256, 0, stream>>>(v1_w, v1t, 512, 512, 1.0f);
  wtrans_kernel<<<dim3(16, 16), 256, 0, stream>>>(o1_w, o1t, 512, 512, 1.0f);
  wtrans_kernel<<<dim3(16, 16), 256, 0, stream>>>(q2_w, q2t, 512, 512, QS);
  wtrans_kernel<<<dim3(24, 16), 256, 0, stream>>>(k2_w, k2t, 768, 512, 1.0f);
  wtrans_kernel<<<dim3(24, 16), 256, 0, stream>>>(v2_w, v2t, 768, 512, 1.0f);
  wtrans_kernel<<<dim3(16, 16), 256, 0, stream>>>(o2_w, o2t, 512, 512, 1.0f);
  wtrans_kernel<<<dim3(16, 128), 256, 0, stream>>>(ff_in_w, ffint, 512, 4096, 1.0f);
  wtrans_kernel<<<dim3(64, 16), 256, 0, stream>>>(ff_out_w, ffoutt, 2048, 512, 1.0f);
  cvt_kernel<<<384, 256, 0, stream>>>(ctx, ctxb);  // 2*256*768

  // ---- self-attention ----
  ln_kernel<<<2048, 256, 0, stream>>>(x, ln1_g, ln1_b, hb);
  // fused Q|K projection: C[8192][1024] (cols 0..511 Q, 512..1023 K)
  gemm_kernel<128, 128, 0><<<dim3(64, 8), 256, 0, stream>>>(
      hb, q1t, nullptr, nullptr, qkb, 8192, 1024, 512, 0, 1024);
  // V^T = v1t @ hb^T -> vtg[vdim][perm(token)], ldo = 8192 (EPI 3)
  gemm_kernel<64, 128, 3><<<dim3(8, 64), 256, 0, stream>>>(
      v1t, hb, nullptr, nullptr, vtg, 512, 8192, 512, 0, 8192);
  attn_kernel<<<dim3(32, 8, 2), 256, 0, stream>>>(qkb, 1024, qkb + 512, 1024,
                                                  vtg, ao, 4096);
  gemm_kernel<64, 128, 1><<<dim3(128, 4), 256, 0, stream>>>(
      ao, o1t, o1_b, x, xr, 8192, 512, 512, 0, 512);

  // ---- cross-attention ----
  ln_kernel<<<2048, 256, 0, stream>>>(xr, ln2_g, ln2_b, hb);
  gemm_kernel<64, 128, 0><<<dim3(128, 4), 256, 0, stream>>>(
      hb, q2t, nullptr, nullptr, qkb, 8192, 512, 512, 0, 512);
  gemm_kernel<64, 128, 0><<<dim3(8, 4), 256, 0, stream>>>(
      ctxb, k2t, nullptr, nullptr, kb, 512, 512, 768, 0, 512);
  gemm_kernel<64, 128, 3><<<dim3(8, 4), 256, 0, stream>>>(
      v2t, ctxb, nullptr, nullptr, vtg2, 512, 512, 768, 0, 512);
  attn_kernel<<<dim3(32, 8, 2), 256, 0, stream>>>(qkb, 512, kb, 512, vtg2, ao,
                                                  256);
  gemm_kernel<64, 128, 1><<<dim3(128, 4), 256, 0, stream>>>(
      ao, o2t, o2_b, xr, xr, 8192, 512, 512, 0, 512);

  // ---- GEGLU FF ----
  ln_kernel<<<2048, 256, 0, stream>>>(xr, ln3_g, ln3_b, hb);
  gemm_kernel<128, 64, 2><<<dim3(64, 32), 256, 0, stream>>>(
      hb, ffint, ff_in_b, nullptr, ffmid, 8192, 2048, 512, 2048, 2048);
  gemm_kernel<64, 128, 1><<<dim3(128, 4), 256, 0, stream>>>(
      ffmid, ffoutt, ff_out_b, xr, (float*)d_out, 8192, 512, 2048, 0, 512);
}

// Round 8
// 307.751 us; speedup vs baseline: 1.9235x; 1.0905x over previous
//
#include <hip/hip_runtime.h>
#include <hip/hip_bf16.h>
#include <cstdint>

// ---------------------------------------------------------------------------
// BasicTransformerBlock: LN -> self-attn -> LN -> cross-attn -> LN -> GEGLU FF
// B=2, N=4096, DIM=512, HEADS=8, D_HEAD=64, CTX: M=256, CD=768, FF_INNER=2048
// fp32 residual/LN, bf16 MFMA GEMMs + flash attention.
// R8: GEMM K-step 64 (two 32-col LDS subtiles per buffer -> half the
//     barriers, 64B rows so no 128B-stride bank conflicts); all weight
//     transposes fused into one descriptor-driven kernel (24 -> 15 launches).
//     Attn unchanged from R7.
// ---------------------------------------------------------------------------

typedef __bf16 bf16_t;
typedef __bf16 bf16x8 __attribute__((ext_vector_type(8)));
typedef float f32x4 __attribute__((ext_vector_type(4)));
typedef float f32x16 __attribute__((ext_vector_type(16)));

__device__ __forceinline__ bf16_t f2bf(float f) { return (bf16_t)f; }

__device__ __forceinline__ f32x4 mfma16(bf16x8 a, bf16x8 b, f32x4 c) {
  return __builtin_amdgcn_mfma_f32_16x16x32_bf16(a, b, c, 0, 0, 0);
}
__device__ __forceinline__ f32x16 mfma32(bf16x8 a, bf16x8 b, f32x16 c) {
  return __builtin_amdgcn_mfma_f32_32x32x16_bf16(a, b, c, 0, 0, 0);
}

__device__ __forceinline__ float gelu_exact(float x) {
  return 0.5f * x * (1.0f + erff(x * 0.70710678118654752f));
}

// async global->LDS, 16B per lane; lds base wave-uniform, global per-lane.
__device__ __forceinline__ void gload_lds16(const bf16_t* g, bf16_t* lds) {
  __builtin_amdgcn_global_load_lds(
      (const __attribute__((address_space(1))) unsigned int*)g,
      (__attribute__((address_space(3))) unsigned int*)lds, 16, 0, 0);
}

// ---------------------------------------------------------------------------
// LayerNorm: one wave per row of 512 fp32; writes bf16.
// ---------------------------------------------------------------------------
__global__ __launch_bounds__(256) void ln_kernel(const float* __restrict__ in,
                                                 const float* __restrict__ gw,
                                                 const float* __restrict__ bw,
                                                 bf16_t* __restrict__ out) {
  int w = threadIdx.x >> 6, l = threadIdx.x & 63;
  size_t row = (size_t)blockIdx.x * 4 + w;
  const float* p = in + row * 512 + l * 8;
  f32x4 va = *(const f32x4*)p;
  f32x4 vb = *(const f32x4*)(p + 4);
  float xs[8] = {va[0], va[1], va[2], va[3], vb[0], vb[1], vb[2], vb[3]};
  float s = 0.f;
#pragma unroll
  for (int j = 0; j < 8; j++) s += xs[j];
#pragma unroll
  for (int m = 1; m < 64; m <<= 1) s += __shfl_xor(s, m);
  float mu = s * (1.0f / 512.0f);
  float v = 0.f;
#pragma unroll
  for (int j = 0; j < 8; j++) { float d = xs[j] - mu; v += d * d; }
#pragma unroll
  for (int m = 1; m < 64; m <<= 1) v += __shfl_xor(v, m);
  float rstd = rsqrtf(v * (1.0f / 512.0f) + 1e-5f);
  f32x4 g0 = *(const f32x4*)(gw + l * 8);
  f32x4 g1 = *(const f32x4*)(gw + l * 8 + 4);
  f32x4 b0 = *(const f32x4*)(bw + l * 8);
  f32x4 b1 = *(const f32x4*)(bw + l * 8 + 4);
  bf16x8 o;
#pragma unroll
  for (int j = 0; j < 4; j++) o[j] = f2bf((xs[j] - mu) * rstd * g0[j] + b0[j]);
#pragma unroll
  for (int j = 0; j < 4; j++) o[4 + j] = f2bf((xs[4 + j] - mu) * rstd * g1[j] + b1[j]);
  *(bf16x8*)(out + row * 512 + l * 8) = o;
}

// ---------------------------------------------------------------------------
// Fused weight transpose+convert: all 10 weights in one launch.
// Each 32x32 tile of W fp32 [K][N] -> Wt bf16 [N][K] (scaled).
// ---------------------------------------------------------------------------
struct WJob {
  const float* W;
  bf16_t* Wt;
  int K;
  int N;
  float sc;
  int tile0;
};
struct WJobs {
  WJob j[10];
};

__global__ __launch_bounds__(256) void wtrans_all_kernel(WJobs jobs) {
  __shared__ float t[32][33];
  int bid = blockIdx.x;
  int i = 0;
#pragma unroll
  for (int q = 1; q < 10; q++)
    if (bid >= jobs.j[q].tile0) i = q;
  WJob jb = jobs.j[i];
  int tt = bid - jb.tile0;
  int ktiles = jb.K >> 5;
  int k0 = (tt % ktiles) * 32, n0 = (tt / ktiles) * 32;
#pragma unroll
  for (int s = 0; s < 4; s++) {
    int idx = threadIdx.x + s * 256;
    int kk = idx >> 5, nn = idx & 31;
    t[kk][nn] = jb.W[(size_t)(k0 + kk) * jb.N + n0 + nn];
  }
  __syncthreads();
#pragma unroll
  for (int s = 0; s < 4; s++) {
    int idx = threadIdx.x + s * 256;
    int nn = idx >> 5, kk = idx & 31;
    jb.Wt[(size_t)(n0 + nn) * jb.K + k0 + kk] = f2bf(t[kk][nn] * jb.sc);
  }
}

// fp32 -> bf16 elementwise (n multiple of 1024)
__global__ __launch_bounds__(256) void cvt_kernel(const float* __restrict__ in,
                                                  bf16_t* __restrict__ out) {
  int i = (blockIdx.x * 256 + threadIdx.x) * 4;
  f32x4 v = *(const f32x4*)(in + i);
  out[i + 0] = f2bf(v[0]);
  out[i + 1] = f2bf(v[1]);
  out[i + 2] = f2bf(v[2]);
  out[i + 3] = f2bf(v[3]);
}

// ---------------------------------------------------------------------------
// GEMM: C[M][N] = A[M][K](bf16) @ B (given as Bt bf16 [N][K]).
// BM in {64,128}, BN in {64,128}; 256 threads, 2x2 wave grid. K-step 64 as
// two 32-col subtiles (64B LDS rows -> conflict-benign), double-buffered,
// global_load_lds width=16 staging, one barrier per 64 K-cols.
// EPI 0: bf16 out. EPI 1: fp32 out = acc + bias + res.
// EPI 2 (BN=64): GEGLU dual-acc, out bf16 = val * gelu(gate).
// EPI 3: bf16 out, column bits 2<->3 swapped (V^T token permutation).
// ---------------------------------------------------------------------------
template <int BM, int BN, int EPI>
__global__ __launch_bounds__(256) void gemm_kernel(
    const bf16_t* __restrict__ A, const bf16_t* __restrict__ Bt,
    const float* __restrict__ bias, const float* __restrict__ res,
    void* __restrict__ outp, int M, int N, int K, int gateOff, int ldo) {
  constexpr int WR = BM / 2;
  constexpr int WN = BN / 2;
  constexpr int MF = WR / 16;
  constexpr int NF = WN / 16;
  constexpr int ABLK = BM / 64;
  constexpr int BROWS = (EPI == 2) ? 2 * BN : BN;
  constexpr int BBLK = BROWS / 64;
  __shared__ bf16_t Al[2][2][BM][32];    // [buf][khalf][row][col]
  __shared__ bf16_t Bl[2][2][BROWS][32];

  int tid = threadIdx.x;
  int w = tid >> 6, l = tid & 63;
  int wr = w >> 1, wc = w & 1;
  int lg = l >> 4, lc = l & 15;
  int m0 = blockIdx.x * BM, n0 = blockIdx.y * BN;

  f32x4 acc[MF][NF] = {};
  f32x4 acc2[MF][NF] = {};

  // staging: lane covers 16B at (srow, scol) within each 64-row block.
  int srow = tid >> 2, scol = (tid & 3) * 8;
  const bf16_t* aP[ABLK];
#pragma unroll
  for (int i = 0; i < ABLK; i++)
    aP[i] = A + (size_t)(m0 + i * 64 + srow) * K + scol;
  const bf16_t* bP[BBLK];
  if (EPI == 2) {
    bP[0] = Bt + (size_t)(n0 + srow) * K + scol;
    bP[1] = Bt + (size_t)(n0 + gateOff + srow) * K + scol;
  } else {
#pragma unroll
    for (int i = 0; i < BBLK; i++)
      bP[i] = Bt + (size_t)(n0 + i * 64 + srow) * K + scol;
  }

  auto STAGE = [&](int buf, int k0) {
#pragma unroll
    for (int kh = 0; kh < 2; kh++) {
#pragma unroll
      for (int i = 0; i < ABLK; i++)
        gload_lds16(aP[i] + k0 + kh * 32, &Al[buf][kh][i * 64 + w * 16][0]);
#pragma unroll
      for (int i = 0; i < BBLK; i++)
        gload_lds16(bP[i] + k0 + kh * 32, &Bl[buf][kh][i * 64 + w * 16][0]);
    }
  };

  int nk = K / 64;
  int cur = 0;
  STAGE(0, 0);
  __syncthreads();  // vmcnt(0) drain + barrier: buf0 ready

  for (int t = 0; t < nk; ++t) {
    if (t + 1 < nk) STAGE(cur ^ 1, (t + 1) * 64);  // in flight during compute

#pragma unroll
    for (int kh = 0; kh < 2; kh++) {
      bf16x8 af[MF];
#pragma unroll
      for (int mi = 0; mi < MF; mi++)
        af[mi] = *(const bf16x8*)&Al[cur][kh][wr * WR + mi * 16 + lc][lg * 8];
      bf16x8 bfr[NF];
#pragma unroll
      for (int ni = 0; ni < NF; ni++)
        bfr[ni] = *(const bf16x8*)&Bl[cur][kh][wc * WN + ni * 16 + lc][lg * 8];
#pragma unroll
      for (int mi = 0; mi < MF; mi++)
#pragma unroll
        for (int ni = 0; ni < NF; ni++)
          acc[mi][ni] = mfma16(af[mi], bfr[ni], acc[mi][ni]);
      if (EPI == 2) {
        bf16x8 bg[NF];
#pragma unroll
        for (int ni = 0; ni < NF; ni++)
          bg[ni] =
              *(const bf16x8*)&Bl[cur][kh][BN + wc * WN + ni * 16 + lc][lg * 8];
#pragma unroll
        for (int mi = 0; mi < MF; mi++)
#pragma unroll
          for (int ni = 0; ni < NF; ni++)
            acc2[mi][ni] = mfma16(af[mi], bg[ni], acc2[mi][ni]);
      }
    }
    __syncthreads();  // next tile landed + read-write hazard
    cur ^= 1;
  }

#pragma unroll
  for (int mi = 0; mi < MF; mi++) {
#pragma unroll
    for (int ni = 0; ni < NF; ni++) {
#pragma unroll
      for (int r = 0; r < 4; r++) {
        int row = m0 + wr * WR + mi * 16 + lg * 4 + r;
        int col = n0 + wc * WN + ni * 16 + lc;
        float v = acc[mi][ni][r];
        if (EPI == 0) {
          ((bf16_t*)outp)[(size_t)row * ldo + col] = f2bf(v);
        } else if (EPI == 3) {
          int cs = (col & ~15) | (lc & 3) | ((lc & 4) << 1) | ((lc & 8) >> 1);
          ((bf16_t*)outp)[(size_t)row * ldo + cs] = f2bf(v);
        } else if (EPI == 1) {
          ((float*)outp)[(size_t)row * ldo + col] =
              v + bias[col] + res[(size_t)row * ldo + col];
        } else {
          float g = acc2[mi][ni][r] + bias[col + gateOff];
          float val = v + bias[col];
          ((bf16_t*)outp)[(size_t)row * ldo + col] = f2bf(val * gelu_exact(g));
        }
      }
    }
  }
}

// ---------------------------------------------------------------------------
// Flash attention on 32x32x16 MFMA (unchanged from R7). Block = 256 threads
// (4 waves); each wave owns 32 q-rows (q = lane&31); block covers 128 q-rows.
// KV tiles 64. QK^T = mfma32(K, Q) -> C[key][q]; softmax lane-local; PV
// A-frags are the lane's own P registers (k-order trick); V tokens bit-2/3
// pre-swapped by EPI=3 GEMM. Row-sums via ones-MFMA. Scale folded into Q.
// ---------------------------------------------------------------------------
__global__ __launch_bounds__(256) void attn_kernel(
    const bf16_t* __restrict__ Q, int ldq, const bf16_t* __restrict__ Kb,
    int ldk, const bf16_t* __restrict__ Vt, bf16_t* __restrict__ O, int Mkv) {
  __shared__ bf16_t Klds[64][72];  // rows = key, cols = d
  __shared__ bf16_t Vlds[64][72];  // rows = d, cols = permuted token

  int qt = blockIdx.x, head = blockIdx.y, b = blockIdx.z;
  int tid = threadIdx.x;
  int w = tid >> 6, l = tid & 63;
  int ql = l & 31, hi = l >> 5;
  int ldv = 2 * Mkv;

  size_t qrow = (size_t)b * 4096 + qt * 128 + w * 32 + ql;
  const bf16_t* qp = Q + qrow * ldq + head * 64 + hi * 8;
  bf16x8 qf[4];
#pragma unroll
  for (int dk = 0; dk < 4; dk++) qf[dk] = *(const bf16x8*)(qp + dk * 16);

  f32x16 o0 = {}, o1 = {};
  f32x16 zacc = {};
  float mrun = -1e30f;

  bf16x8 vones;
#pragma unroll
  for (int j = 0; j < 8; j++) vones[j] = f2bf(1.0f);

  int key0 = tid >> 2, dc0 = (tid & 3) * 16;
  const bf16_t* kp = Kb + ((size_t)b * Mkv + key0) * ldk + head * 64 + dc0;
  const bf16_t* vp = Vt + (size_t)(head * 64 + key0) * ldv + b * Mkv + dc0;

  bf16x8 kc0 = *(const bf16x8*)kp, kc1 = *(const bf16x8*)(kp + 8);
  bf16x8 vc0 = *(const bf16x8*)vp, vc1 = *(const bf16x8*)(vp + 8);

  for (int t0 = 0; t0 < Mkv; t0 += 64) {
    __syncthreads();
    *(bf16x8*)&Klds[key0][dc0] = kc0;
    *(bf16x8*)&Klds[key0][dc0 + 8] = kc1;
    *(bf16x8*)&Vlds[key0][dc0] = vc0;
    *(bf16x8*)&Vlds[key0][dc0 + 8] = vc1;
    __syncthreads();

    if (t0 + 64 < Mkv) {
      kp += (size_t)64 * ldk;
      vp += 64;
      kc0 = *(const bf16x8*)kp;
      kc1 = *(const bf16x8*)(kp + 8);
      vc0 = *(const bf16x8*)vp;
      vc1 = *(const bf16x8*)(vp + 8);
    }

    f32x16 s0 = {}, s1 = {};
    __builtin_amdgcn_s_setprio(1);
#pragma unroll
    for (int dk = 0; dk < 4; dk++) {
      bf16x8 a0 = *(const bf16x8*)&Klds[ql][dk * 16 + hi * 8];
      bf16x8 a1 = *(const bf16x8*)&Klds[32 + ql][dk * 16 + hi * 8];
      s0 = mfma32(a0, qf[dk], s0);
      s1 = mfma32(a1, qf[dk], s1);
    }
    __builtin_amdgcn_s_setprio(0);

    float tmax = s0[0];
#pragma unroll
    for (int r = 1; r < 16; r++) tmax = fmaxf(tmax, s0[r]);
#pragma unroll
    for (int r = 0; r < 16; r++) tmax = fmaxf(tmax, s1[r]);
    tmax = fmaxf(tmax, __shfl_xor(tmax, 32));

    if (!__all(tmax <= mrun + 8.0f)) {
      float mnew = fmaxf(mrun, tmax);
      float resc = __builtin_amdgcn_exp2f(mrun - mnew);
      mrun = mnew;
#pragma unroll
      for (int r = 0; r < 16; r++) {
        float f = __shfl(resc, (r & 3) + 8 * (r >> 2) + 4 * hi);
        o0[r] *= f;
        o1[r] *= f;
        zacc[r] *= f;
      }
    }

    bf16x8 pa[4];
#pragma unroll
    for (int m = 0; m < 4; m++) {
#pragma unroll
      for (int j = 0; j < 8; j++) {
        float sv = (m < 2) ? s0[(m & 1) * 8 + j] : s1[(m & 1) * 8 + j];
        pa[m][j] = f2bf(__builtin_amdgcn_exp2f(sv - mrun));
      }
    }

    __builtin_amdgcn_s_setprio(1);
#pragma unroll
    for (int m = 0; m < 4; m++) {
      zacc = mfma32(pa[m], vones, zacc);
      bf16x8 vb0 = *(const bf16x8*)&Vlds[ql][m * 16 + hi * 8];
      bf16x8 vb1 = *(const bf16x8*)&Vlds[32 + ql][m * 16 + hi * 8];
      o0 = mfma32(pa[m], vb0, o0);
      o1 = mfma32(pa[m], vb1, o1);
    }
    __builtin_amdgcn_s_setprio(0);
  }

  size_t ob = ((size_t)b * 4096 + qt * 128 + w * 32) * 512 + head * 64;
#pragma unroll
  for (int r = 0; r < 16; r++) {
    float inv = 1.0f / zacc[r];
    int q = (r & 3) + 8 * (r >> 2) + 4 * hi;
    O[ob + (size_t)q * 512 + ql] = f2bf(o0[r] * inv);
    O[ob + (size_t)q * 512 + 32 + ql] = f2bf(o1[r] * inv);
  }
}

// ---------------------------------------------------------------------------
extern "C" void kernel_launch(void* const* d_in, const int* in_sizes, int n_in,
                              void* d_out, int out_size, void* d_ws,
                              size_t ws_size, hipStream_t stream) {
  const float* x = (const float*)d_in[0];
  const float* ctx = (const float*)d_in[1];
  const float* q1_w = (const float*)d_in[2];
  const float* k1_w = (const float*)d_in[3];
  const float* v1_w = (const float*)d_in[4];
  const float* o1_w = (const float*)d_in[5];
  const float* o1_b = (const float*)d_in[6];
  const float* q2_w = (const float*)d_in[7];
  const float* k2_w = (const float*)d_in[8];
  const float* v2_w = (const float*)d_in[9];
  const float* o2_w = (const float*)d_in[10];
  const float* o2_b = (const float*)d_in[11];
  const float* ff_in_w = (const float*)d_in[12];
  const float* ff_in_b = (const float*)d_in[13];
  const float* ff_out_w = (const float*)d_in[14];
  const float* ff_out_b = (const float*)d_in[15];
  const float* ln1_g = (const float*)d_in[16];
  const float* ln1_b = (const float*)d_in[17];
  const float* ln2_g = (const float*)d_in[18];
  const float* ln2_b = (const float*)d_in[19];
  const float* ln3_g = (const float*)d_in[20];
  const float* ln3_b = (const float*)d_in[21];

  char* ws = (char*)d_ws;
  float* xr = (float*)(ws + 0);                    // 16.78 MB fp32 residual
  bf16_t* hb = (bf16_t*)(ws + 16777216);           // 8.39 MB LN output
  bf16_t* qkb = (bf16_t*)(ws + 25165824);          // 16.78 MB [8192][1024]
  bf16_t* ao = (bf16_t*)(ws + 41943040);           // 8.39 MB
  bf16_t* ffmid = qkb;                             // alias qkb+ao (33.55 MB)
  bf16_t* kb = (bf16_t*)(ws + 50331648);           // 0.52 MB cross K
  bf16_t* vtg2 = (bf16_t*)(ws + 50855936);         // 0.52 MB cross V^T
  bf16_t* ctxb = (bf16_t*)(ws + 51380224);         // 0.79 MB
  bf16_t* wts = (bf16_t*)(ws + 58720256);          // 11.01 MB bf16 weights^T
  bf16_t* vtg = (bf16_t*)(ws + 69730304);          // 8.39 MB V^T [512][8192]

  bf16_t* q1t = wts + 0;        // q1t,k1t adjacent -> fused Q|K weight
  bf16_t* k1t = wts + 262144;
  bf16_t* v1t = wts + 524288;
  bf16_t* o1t = wts + 786432;
  bf16_t* q2t = wts + 1048576;
  bf16_t* k2t = wts + 1310720;
  bf16_t* v2t = wts + 1703936;
  bf16_t* o2t = wts + 2097152;
  bf16_t* ffint = wts + 2359296;
  bf16_t* ffoutt = wts + 4456448;

  const float QS = 0.125f * 1.44269504f;  // attn scale * log2(e) -> into Q

  // fused weight transposes: 10 jobs, one launch
  WJobs jobs;
  auto setj = [&](int i, const float* W, bf16_t* Wt, int K, int N, float sc,
                  int tile0) {
    jobs.j[i] = WJob{W, Wt, K, N, sc, tile0};
  };
  setj(0, q1_w, q1t, 512, 512, QS, 0);
  setj(1, k1_w, k1t, 512, 512, 1.0f, 256);
  setj(2, v1_w, v1t, 512, 512, 1.0f, 512);
  setj(3, o1_w, o1t, 512, 512, 1.0f, 768);
  setj(4, q2_w, q2t, 512, 512, QS, 1024);
  setj(5, k2_w, k2t, 768, 512, 1.0f, 1280);
  setj(6, v2_w, v2t, 768, 512, 1.0f, 1664);
  setj(7, o2_w, o2t, 512, 512, 1.0f, 2048);
  setj(8, ff_in_w, ffint, 512, 4096, 1.0f, 2304);
  setj(9, ff_out_w, ffoutt, 2048, 512, 1.0f, 4352);
  wtrans_all_kernel<<<5376, 256, 0, stream>>>(jobs);
  cvt_kernel<<<384, 256, 0, stream>>>(ctx, ctxb);  // 2*256*768

  // ---- self-attention ----
  ln_kernel<<<2048, 256, 0, stream>>>(x, ln1_g, ln1_b, hb);
  // fused Q|K projection: C[8192][1024] (cols 0..511 Q, 512..1023 K)
  gemm_kernel<128, 128, 0><<<dim3(64, 8), 256, 0, stream>>>(
      hb, q1t, nullptr, nullptr, qkb, 8192, 1024, 512, 0, 1024);
  // V^T = v1t @ hb^T -> vtg[vdim][perm(token)], ldo = 8192 (EPI 3)
  gemm_kernel<64, 128, 3><<<dim3(8, 64), 256, 0, stream>>>(
      v1t, hb, nullptr, nullptr, vtg, 512, 8192, 512, 0, 8192);
  attn_kernel<<<dim3(32, 8, 2), 256, 0, stream>>>(qkb, 1024, qkb + 512, 1024,
                                                  vtg, ao, 4096);
  gemm_kernel<64, 128, 1><<<dim3(128, 4), 256, 0, stream>>>(
      ao, o1t, o1_b, x, xr, 8192, 512, 512, 0, 512);

  // ---- cross-attention ----
  ln_kernel<<<2048, 256, 0, stream>>>(xr, ln2_g, ln2_b, hb);
  gemm_kernel<64, 128, 0><<<dim3(128, 4), 256, 0, stream>>>(
      hb, q2t, nullptr, nullptr, qkb, 8192, 512, 512, 0, 512);
  gemm_kernel<64, 128, 0><<<dim3(8, 4), 256, 0, stream>>>(
      ctxb, k2t, nullptr, nullptr, kb, 512, 512, 768, 0, 512);
  gemm_kernel<64, 128, 3><<<dim3(8, 4), 256, 0, stream>>>(
      v2t, ctxb, nullptr, nullptr, vtg2, 512, 512, 768, 0, 512);
  attn_kernel<<<dim3(32, 8, 2), 256, 0, stream>>>(qkb, 512, kb, 512, vtg2, ao,
                                                  256);
  gemm_kernel<64, 128, 1><<<dim3(128, 4), 256, 0, stream>>>(
      ao, o2t, o2_b, xr, xr, 8192, 512, 512, 0, 512);

  // ---- GEGLU FF ----
  ln_kernel<<<2048, 256, 0, stream>>>(xr, ln3_g, ln3_b, hb);
  gemm_kernel<128, 64, 2><<<dim3(64, 32), 256, 0, stream>>>(
      hb, ffint, ff_in_b, nullptr, ffmid, 8192, 2048, 512, 2048, 2048);
  gemm_kernel<64, 128, 1><<<dim3(128, 4), 256, 0, stream>>>(
      ffmid, ffoutt, ff_out_b, xr, (float*)d_out, 8192, 512, 2048, 0, 512);
}